// Round 8
// baseline (221.602 us; speedup 1.0000x reference)
//
#include <hip/hip_runtime.h>

typedef unsigned int u32;
typedef unsigned short u16;

typedef short bf16x8 __attribute__((ext_vector_type(8)));
typedef float f32x4 __attribute__((ext_vector_type(4)));

#define GM 2048      // B
#define GN 11008     // O
#define GK 4096      // I
#define NGRP 32      // N = I/G
#define GSZ 128      // G

#define CAST_G(p) ((const __attribute__((address_space(1))) void*)(p))
#define CAST_L(p) ((__attribute__((address_space(3))) void*)(p))
#define BAR() __builtin_amdgcn_s_barrier()
#define SCHED0() __builtin_amdgcn_sched_barrier(0)

__device__ __forceinline__ u16 f2bf(float f) {
    u32 u = __builtin_bit_cast(u32, f);
    u32 r = (u + 0x7FFFu + ((u >> 16) & 1u)) >> 16;
    return (u16)r;
}

// ---------------------------------------------------------------------------
// Prep (merged): rotate x -> rx (bf16) AND dequant packed 3-bit -> wq bf16.
// Both BW-bound; one dispatch saves a launch gap and lets them share BW.
// ---------------------------------------------------------------------------
__device__ __forceinline__ float cent3(int i) {
    int m3 = (i >= 4) ? (i - 4) : (3 - i);
    float mag = (m3 >= 2) ? ((m3 == 3) ? 2.1519f : 1.3439f)
                          : ((m3 == 1) ? 0.756f  : 0.2451f);
    return (i >= 4) ? mag : -mag;
}

#define ROT_BLOCKS (GM * NGRP / 4)             // 16384
#define DQ_BLOCKS  (GN * NGRP * 4 / 256)       // 5504

__global__ __launch_bounds__(256) void prep_kernel(
    const float* __restrict__ x, const float* __restrict__ s1,
    const float* __restrict__ s2, u32* __restrict__ rx,
    const u32* __restrict__ p32, const float* __restrict__ norms,
    u16* __restrict__ wq) {
    if (blockIdx.x < ROT_BLOCKS) {
        int gid  = blockIdx.x * 256 + threadIdx.x;
        int grp  = gid >> 6;
        int lane = gid & 63;

        const float2* xp = (const float2*)(x + (size_t)grp * GSZ);
        float2 xv  = xp[lane];
        float2 s1v = ((const float2*)s1)[lane];
        float2 s2v = ((const float2*)s2)[lane];

        float e0 = xv.x * s1v.x;
        float e1 = xv.y * s1v.y;
        {
            float a = e0 + e1, b = e0 - e1;
            e0 = a; e1 = b;
        }
        #pragma unroll
        for (int hb = 1; hb <= 32; hb <<= 1) {
            float t0 = __shfl_xor(e0, hb, 64);
            float t1 = __shfl_xor(e1, hb, 64);
            bool up = (lane & hb) != 0;
            e0 = up ? (t0 - e0) : (e0 + t0);
            e1 = up ? (t1 - e1) : (e1 + t1);
        }
        const float inv = 0.08838834764831845f;   // 1/sqrt(128)
        u32 lo = f2bf(e0 * s2v.x * inv);
        u32 hi = f2bf(e1 * s2v.y * inv);
        rx[gid] = lo | (hi << 16);
    } else {
        int u = (blockIdx.x - ROT_BLOCKS) * 256 + threadIdx.x;
        int g_idx = u >> 2;

        float scale = norms[g_idx] * 0.08838834764831845f;

        u32 w0 = p32[(size_t)u * 3 + 0];
        u32 w1 = p32[(size_t)u * 3 + 1];
        u32 w2 = p32[(size_t)u * 3 + 2];

        u32 tri[4];
        if (((w0 | w1 | w2) & 0xFFFFFF00u) == 0u) {
            const u32* pi = p32 + (size_t)u * 12;
            u32 b[12];
            #pragma unroll
            for (int k = 0; k < 12; ++k) b[k] = pi[k];
            #pragma unroll
            for (int t = 0; t < 4; ++t)
                tri[t] = b[3*t] | (b[3*t+1] << 8) | (b[3*t+2] << 16);
        } else {
            tri[0] = w0 & 0xFFFFFFu;
            tri[1] = (w0 >> 24) | ((w1 & 0xFFFFu) << 8);
            tri[2] = (w1 >> 16) | ((w2 & 0xFFu) << 16);
            tri[3] = w2 >> 8;
        }

        u32 ow[16];
        #pragma unroll
        for (int t = 0; t < 4; ++t) {
            u32 v = tri[t];
            #pragma unroll
            for (int k = 0; k < 4; ++k) {
                int i0 = (int)((v >> (6*k))     & 7u);
                int i1 = (int)((v >> (6*k + 3)) & 7u);
                u32 lo = f2bf(cent3(i0) * scale);
                u32 hi = f2bf(cent3(i1) * scale);
                ow[t*4 + k] = lo | (hi << 16);
            }
        }
        u32* op = (u32*)(wq + (size_t)u * 32);
        #pragma unroll
        for (int k = 0; k < 16; ++k) op[k] = ow[k];
    }
}

// ---------------------------------------------------------------------------
// Shared: async half-tile staging (64 rows x 64 cols bf16 per call)
// ---------------------------------------------------------------------------
__device__ __forceinline__ void stage_half(const u16* g, char* ldst, int rowOff, int tt) {
    __builtin_amdgcn_global_load_lds(CAST_G(g + (size_t)rowOff * GK + tt * 64),
                                     CAST_L(ldst), 16, 0, 0);
    __builtin_amdgcn_global_load_lds(CAST_G(g + (size_t)(rowOff + 64) * GK + tt * 64),
                                     CAST_L(ldst + 8192), 16, 0, 0);
}

// ---------------------------------------------------------------------------
// Big path: 256x256 tile, BK=64, 4 phases/K-tile, 2-deep 128 KiB LDS,
// **cross-phase read-ahead**: P1 reads b1F(t), P2 reads aFy(t), P4 reads
// aFx(t+1)+b0F(t+1) (other buffer). Every cross-tile read sits after a
// {vmcnt; BAR} pair: vmcnt(8) end-of-P3 (completes A0/B0(t+1) for P4's
// reads), vmcnt(6) end-of-P4 (completes B1/A1(t+1) for P1/P2(t+1)).
// Outstanding-queue invariant: 6 at P1-top -> 8/10/12 -> vm8 -> 10 -> vm6 -> 6.
// Frags loop-carried (single-buffered; liveness disjoint). T2 both-sides XOR
// swizzle, T5 setprio unchanged from r7.
// ---------------------------------------------------------------------------
template<int BUF>
__device__ __forceinline__ void ktile4(int t, char* lds,
                                       const u16* gA, const u16* gB,
                                       int sB, int aBase, int bBase, int sw0, int sw1,
                                       bf16x8 (&aFx)[4][2], bf16x8 (&aFy)[4][2],
                                       bf16x8 (&b0F)[2][2], bf16x8 (&b1F)[2][2],
                                       f32x4 (&acc)[8][4]) {
    const int AB  = BUF * 32768;
    const int BB  = 65536 + BUF * 32768;
    const int ABo = (BUF ^ 1) * 32768;
    const int BBo = 65536 + (BUF ^ 1) * 32768;

    bool s1 = (t < 63), s2 = (t < 62);

    // ---- P1: read b1F(t); stage B1(t+1)->other; MFMA (mh0,nh0) = aFx*b0F
    #pragma unroll
    for (int nj = 0; nj < 2; ++nj) {
        b1F[nj][0] = *(const bf16x8*)(lds + BB + 16384 + bBase + nj * 8192 + sw0);
        b1F[nj][1] = *(const bf16x8*)(lds + BB + 16384 + bBase + nj * 8192 + sw1);
    }
    if (s1) stage_half(gB, lds + BBo + 16384 + sB, 128, t + 1);
    SCHED0(); BAR(); SCHED0();
    __builtin_amdgcn_s_setprio(1);
    #pragma unroll
    for (int mj = 0; mj < 4; ++mj)
        #pragma unroll
        for (int nj = 0; nj < 2; ++nj)
            #pragma unroll
            for (int kk = 0; kk < 2; ++kk)
                acc[mj][nj] = __builtin_amdgcn_mfma_f32_16x16x32_bf16(
                    aFx[mj][kk], b0F[nj][kk], acc[mj][nj], 0, 0, 0);
    __builtin_amdgcn_s_setprio(0);
    BAR();

    // ---- P2: read aFy(t); stage A0(t+2)->this; MFMA (mh0,nh1) = aFx*b1F
    #pragma unroll
    for (int mj = 0; mj < 4; ++mj) {
        aFy[mj][0] = *(const bf16x8*)(lds + AB + 16384 + aBase + mj * 4096 + sw0);
        aFy[mj][1] = *(const bf16x8*)(lds + AB + 16384 + aBase + mj * 4096 + sw1);
    }
    if (s2) stage_half(gA, lds + AB + sB, 0, t + 2);
    SCHED0(); BAR(); SCHED0();
    __builtin_amdgcn_s_setprio(1);
    #pragma unroll
    for (int mj = 0; mj < 4; ++mj)
        #pragma unroll
        for (int nj = 0; nj < 2; ++nj)
            #pragma unroll
            for (int kk = 0; kk < 2; ++kk)
                acc[mj][2 + nj] = __builtin_amdgcn_mfma_f32_16x16x32_bf16(
                    aFx[mj][kk], b1F[nj][kk], acc[mj][2 + nj], 0, 0, 0);
    __builtin_amdgcn_s_setprio(0);
    BAR();

    // ---- P3: stage B0(t+2)->this; MFMA (mh1,nh0) = aFy*b0F; vmcnt(8)
    if (s2) stage_half(gB, lds + BB + sB, 0, t + 2);
    SCHED0(); BAR(); SCHED0();
    __builtin_amdgcn_s_setprio(1);
    #pragma unroll
    for (int mj = 0; mj < 4; ++mj)
        #pragma unroll
        for (int nj = 0; nj < 2; ++nj)
            #pragma unroll
            for (int kk = 0; kk < 2; ++kk)
                acc[4 + mj][nj] = __builtin_amdgcn_mfma_f32_16x16x32_bf16(
                    aFy[mj][kk], b0F[nj][kk], acc[4 + mj][nj], 0, 0, 0);
    __builtin_amdgcn_s_setprio(0);
    if (s2) { asm volatile("s_waitcnt vmcnt(8)" ::: "memory"); }
    else    { asm volatile("s_waitcnt vmcnt(0)" ::: "memory"); }
    BAR();

    // ---- P4: read aFx(t+1)+b0F(t+1) (other buf); stage A1(t+2)->this;
    //          MFMA (mh1,nh1) = aFy*b1F; vmcnt(6)
    if (s1) {
        SCHED0();
        #pragma unroll
        for (int mj = 0; mj < 4; ++mj) {
            aFx[mj][0] = *(const bf16x8*)(lds + ABo + aBase + mj * 4096 + sw0);
            aFx[mj][1] = *(const bf16x8*)(lds + ABo + aBase + mj * 4096 + sw1);
        }
        #pragma unroll
        for (int nj = 0; nj < 2; ++nj) {
            b0F[nj][0] = *(const bf16x8*)(lds + BBo + bBase + nj * 8192 + sw0);
            b0F[nj][1] = *(const bf16x8*)(lds + BBo + bBase + nj * 8192 + sw1);
        }
    }
    if (s2) stage_half(gA, lds + AB + 16384 + sB, 128, t + 2);
    SCHED0(); BAR(); SCHED0();
    __builtin_amdgcn_s_setprio(1);
    #pragma unroll
    for (int mj = 0; mj < 4; ++mj)
        #pragma unroll
        for (int nj = 0; nj < 2; ++nj)
            #pragma unroll
            for (int kk = 0; kk < 2; ++kk)
                acc[4 + mj][2 + nj] = __builtin_amdgcn_mfma_f32_16x16x32_bf16(
                    aFy[mj][kk], b1F[nj][kk], acc[4 + mj][2 + nj], 0, 0, 0);
    __builtin_amdgcn_s_setprio(0);
    if (s2) { asm volatile("s_waitcnt vmcnt(6)" ::: "memory"); }
    else    { asm volatile("s_waitcnt vmcnt(0)" ::: "memory"); }
    BAR();
}

__device__ __forceinline__ void gemm_big(int tau, int tid, char* lds,
                                         const u16* A, const u16* Bw, float* C) {
    int lane = tid & 63;
    int wv   = tid >> 6;
    int wr   = wv >> 2;
    int wc   = wv & 3;

    int m0 = (tau & 7) * 256;        // XCD x owns A panel x (L2-resident)
    int n0 = (tau >> 3) * 256;

    int srow = tid >> 3;
    int c16  = (tid & 7) ^ (srow & 7);
    const u16* gA = A  + (size_t)(m0 + srow) * GK + c16 * 8;
    const u16* gB = Bw + (size_t)(n0 + srow) * GK + c16 * 8;
    int sB = wv * 1024;

    int aBase = (wr * 16 + (lane & 15)) * 128;
    int bBase = (wc * 16 + (lane & 15)) * 128;
    int sw0 = (((lane >> 4))     ^ (lane & 7)) << 4;
    int sw1 = (((lane >> 4) + 4) ^ (lane & 7)) << 4;

    f32x4 acc[8][4] = {};
    bf16x8 aFx[4][2], aFy[4][2], b0F[2][2], b1F[2][2];

    // prologue: A0(0),B0(0),A1(0),B1(0),A0(1),B0(1),A1(1) = 14 loads;
    // vmcnt(6) completes tile0; BAR; prologue reads aFx(0),b0F(0).
    stage_half(gA, lds + sB,                 0,   0);   // A0(0)
    stage_half(gB, lds + 65536 + sB,         0,   0);   // B0(0)
    stage_half(gA, lds + 16384 + sB,         128, 0);   // A1(0)
    stage_half(gB, lds + 65536 + 16384 + sB, 128, 0);   // B1(0)
    stage_half(gA, lds + 32768 + sB,         0,   1);   // A0(1)
    stage_half(gB, lds + 65536 + 32768 + sB, 0,   1);   // B0(1)
    stage_half(gA, lds + 32768 + 16384 + sB, 128, 1);   // A1(1)
    asm volatile("s_waitcnt vmcnt(6)" ::: "memory");
    BAR(); SCHED0();
    #pragma unroll
    for (int mj = 0; mj < 4; ++mj) {
        aFx[mj][0] = *(const bf16x8*)(lds + aBase + mj * 4096 + sw0);
        aFx[mj][1] = *(const bf16x8*)(lds + aBase + mj * 4096 + sw1);
    }
    #pragma unroll
    for (int nj = 0; nj < 2; ++nj) {
        b0F[nj][0] = *(const bf16x8*)(lds + 65536 + bBase + nj * 8192 + sw0);
        b0F[nj][1] = *(const bf16x8*)(lds + 65536 + bBase + nj * 8192 + sw1);
    }

    for (int tt = 0; tt < 64; tt += 2) {
        ktile4<0>(tt,     lds, gA, gB, sB, aBase, bBase, sw0, sw1,
                  aFx, aFy, b0F, b1F, acc);
        ktile4<1>(tt + 1, lds, gA, gB, sB, aBase, bBase, sw0, sw1,
                  aFx, aFy, b0F, b1F, acc);
    }

    int cr = (lane >> 4) * 4;
    int cc = lane & 15;
    #pragma unroll
    for (int mh = 0; mh < 2; ++mh)
        #pragma unroll
        for (int mj = 0; mj < 4; ++mj)
            #pragma unroll
            for (int nh = 0; nh < 2; ++nh)
                #pragma unroll
                for (int nj = 0; nj < 2; ++nj) {
                    float* cp = C + (size_t)(m0 + mh * 128 + wr * 16 + mj * 32 + cr) * GN
                                  + (n0 + nh * 128 + wc * 16 + nj * 64 + cc);
                    #pragma unroll
                    for (int j = 0; j < 4; ++j)
                        __builtin_nontemporal_store(acc[mh * 4 + mj][nh * 2 + nj][j],
                                                    cp + (size_t)j * GN);
                }
}

// ---------------------------------------------------------------------------
// Tail path: 128x256 tile, full-K, 3-deep 144 KiB LDS, 2 phases/K-tile,
// vmcnt(6). (r4/r7-verified, unchanged)
// ---------------------------------------------------------------------------
template<int BUF>
__device__ __forceinline__ void ktile2(int t, char* lds,
                                       const u16* gA, const u16* gB,
                                       int sB, int aBase, int bBase, int sw0, int sw1,
                                       f32x4 (&acc)[4][4]) {
    const int AB  = BUF * 16384;
    const int BB  = 49152 + BUF * 32768;
    const int NB  = (BUF + 2 >= 3) ? (BUF - 1) : (BUF + 2);
    const int ABn = NB * 16384;
    const int BBn = 49152 + NB * 32768;

    bf16x8 aF[4][2], bF[2][2];
    bool s2 = (t < 62);

    #pragma unroll
    for (int mj = 0; mj < 4; ++mj) {
        aF[mj][0] = *(const bf16x8*)(lds + AB + aBase + mj * 4096 + sw0);
        aF[mj][1] = *(const bf16x8*)(lds + AB + aBase + mj * 4096 + sw1);
    }
    #pragma unroll
    for (int nj = 0; nj < 2; ++nj) {
        bF[nj][0] = *(const bf16x8*)(lds + BB + bBase + nj * 8192 + sw0);
        bF[nj][1] = *(const bf16x8*)(lds + BB + bBase + nj * 8192 + sw1);
    }
    if (s2) {
        stage_half(gA, lds + ABn + sB, 0, t + 2);
        stage_half(gB, lds + BBn + sB, 0, t + 2);
    }
    BAR(); SCHED0();
    __builtin_amdgcn_s_setprio(1);
    #pragma unroll
    for (int mj = 0; mj < 4; ++mj)
        #pragma unroll
        for (int nj = 0; nj < 2; ++nj)
            #pragma unroll
            for (int kk = 0; kk < 2; ++kk)
                acc[mj][nj] = __builtin_amdgcn_mfma_f32_16x16x32_bf16(
                    aF[mj][kk], bF[nj][kk], acc[mj][nj], 0, 0, 0);
    __builtin_amdgcn_s_setprio(0);
    BAR();

    #pragma unroll
    for (int nj = 0; nj < 2; ++nj) {
        bF[nj][0] = *(const bf16x8*)(lds + BB + 16384 + bBase + nj * 8192 + sw0);
        bF[nj][1] = *(const bf16x8*)(lds + BB + 16384 + bBase + nj * 8192 + sw1);
    }
    if (s2) stage_half(gB, lds + BBn + 16384 + sB, 128, t + 2);
    BAR(); SCHED0();
    __builtin_amdgcn_s_setprio(1);
    #pragma unroll
    for (int mj = 0; mj < 4; ++mj)
        #pragma unroll
        for (int nj = 0; nj < 2; ++nj)
            #pragma unroll
            for (int kk = 0; kk < 2; ++kk)
                acc[mj][2 + nj] = __builtin_amdgcn_mfma_f32_16x16x32_bf16(
                    aF[mj][kk], bF[nj][kk], acc[mj][2 + nj], 0, 0, 0);
    __builtin_amdgcn_s_setprio(0);
    if (s2) { asm volatile("s_waitcnt vmcnt(6)" ::: "memory"); }
    else    { asm volatile("s_waitcnt vmcnt(0)" ::: "memory"); }
    BAR();
}

__device__ __forceinline__ void gemm_tail(int bid, int tid, char* lds,
                                          const u16* A, const u16* Bw, float* C) {
    int lane = tid & 63;
    int wv   = tid >> 6;
    int wr   = wv >> 2;
    int wc   = wv & 3;

    int swz = (bid & 7) * 22 + (bid >> 3);     // 176 = 8 * 22
    int nt  = swz >> 4;
    int mh  = swz & 15;
    int m0  = mh * 128;
    int n0  = 8192 + nt * 256;

    int srow = tid >> 3;
    int c16  = (tid & 7) ^ (srow & 7);
    const u16* gA = A  + (size_t)(m0 + srow) * GK + c16 * 8;
    const u16* gB = Bw + (size_t)(n0 + srow) * GK + c16 * 8;
    int sB = wv * 1024;

    int aBase = (wr * 16 + (lane & 15)) * 128;
    int bBase = (wc * 16 + (lane & 15)) * 128;
    int sw0 = (((lane >> 4))     ^ (lane & 7)) << 4;
    int sw1 = (((lane >> 4) + 4) ^ (lane & 7)) << 4;

    f32x4 acc[4][4] = {};

    stage_half(gA, lds + sB,                 0,   0);
    stage_half(gB, lds + 49152 + sB,         0,   0);
    stage_half(gB, lds + 49152 + 16384 + sB, 128, 0);
    stage_half(gA, lds + 16384 + sB,         0,   1);
    stage_half(gB, lds + 81920 + sB,         0,   1);
    stage_half(gB, lds + 81920 + 16384 + sB, 128, 1);
    asm volatile("s_waitcnt vmcnt(6)" ::: "memory");
    BAR();

    for (int tt = 0; tt < 63; tt += 3) {
        ktile2<0>(tt,     lds, gA, gB, sB, aBase, bBase, sw0, sw1, acc);
        ktile2<1>(tt + 1, lds, gA, gB, sB, aBase, bBase, sw0, sw1, acc);
        ktile2<2>(tt + 2, lds, gA, gB, sB, aBase, bBase, sw0, sw1, acc);
    }
    ktile2<0>(63, lds, gA, gB, sB, aBase, bBase, sw0, sw1, acc);

    int cr = (lane >> 4) * 4;
    int cc = lane & 15;
    #pragma unroll
    for (int mj = 0; mj < 4; ++mj)
        #pragma unroll
        for (int nj = 0; nj < 4; ++nj) {
            float* cp = C + (size_t)(m0 + wr * 16 + mj * 32 + cr) * GN
                          + (n0 + wc * 16 + nj * 64 + cc);
            #pragma unroll
            for (int j = 0; j < 4; ++j)
                __builtin_nontemporal_store(acc[mj][nj][j], cp + (size_t)j * GN);
        }
}

// ---------------------------------------------------------------------------
// Merged GEMM: 432 blocks. 0..255 = 256x256 full tiles (n < 8192),
// 256..431 = 128x256 full-K tail tiles (n >= 8192). LPT order.
// ---------------------------------------------------------------------------
__global__ __launch_bounds__(512, 1) void gemm_all_kernel(
    const u16* __restrict__ A, const u16* __restrict__ Bw,
    float* __restrict__ C) {
    extern __shared__ char lds[];
    int bid = blockIdx.x;
    if (bid < 256) gemm_big (bid,       threadIdx.x, lds, A, Bw, C);
    else           gemm_tail(bid - 256, threadIdx.x, lds, A, Bw, C);
}

// ---------------------------------------------------------------------------
extern "C" void kernel_launch(void* const* d_in, const int* in_sizes, int n_in,
                              void* d_out, int out_size, void* d_ws, size_t ws_size,
                              hipStream_t stream) {
    const float* x      = (const float*)d_in[0];
    const void*  packed = d_in[1];
    const float* norms  = (const float*)d_in[2];
    const float* s1     = (const float*)d_in[4];
    const float* s2     = (const float*)d_in[5];
    float* out          = (float*)d_out;

    size_t rx_bytes = (size_t)GM * GK * 2;
    size_t wq_bytes = (size_t)GN * GK * 2;
    if (ws_size < rx_bytes + wq_bytes) return;

    u16* rx = (u16*)d_ws;
    u16* wq = rx + (size_t)GM * GK;

    prep_kernel<<<dim3(ROT_BLOCKS + DQ_BLOCKS), dim3(256), 0, stream>>>(
        x, s1, s2, (u32*)rx, (const u32*)packed, norms, wq);

    hipFuncSetAttribute((const void*)gemm_all_kernel,
                        hipFuncAttributeMaxDynamicSharedMemorySize, 147456);
    gemm_all_kernel<<<dim3(432), dim3(512), 147456, stream>>>(rx, wq, out);
}

// Round 9
// 213.823 us; speedup vs baseline: 1.0364x; 1.0364x over previous
//
#include <hip/hip_runtime.h>

typedef unsigned int u32;
typedef unsigned short u16;

typedef short bf16x8 __attribute__((ext_vector_type(8)));
typedef float f32x4 __attribute__((ext_vector_type(4)));

#define GM 2048      // B
#define GN 11008     // O
#define GK 4096      // I
#define NGRP 32      // N = I/G
#define GSZ 128      // G

#define CAST_G(p) ((const __attribute__((address_space(1))) void*)(p))
#define CAST_L(p) ((__attribute__((address_space(3))) void*)(p))
#define BAR() __builtin_amdgcn_s_barrier()
#define SCHED0() __builtin_amdgcn_sched_barrier(0)

__device__ __forceinline__ u16 f2bf(float f) {
    u32 u = __builtin_bit_cast(u32, f);
    u32 r = (u + 0x7FFFu + ((u >> 16) & 1u)) >> 16;
    return (u16)r;
}

// ---------------------------------------------------------------------------
// Prep (merged): rotate x -> rx (bf16) AND dequant packed 3-bit -> wq bf16.
// ~21.6 us measured (r8) at the 156 MB traffic roofline.
// ---------------------------------------------------------------------------
__device__ __forceinline__ float cent3(int i) {
    int m3 = (i >= 4) ? (i - 4) : (3 - i);
    float mag = (m3 >= 2) ? ((m3 == 3) ? 2.1519f : 1.3439f)
                          : ((m3 == 1) ? 0.756f  : 0.2451f);
    return (i >= 4) ? mag : -mag;
}

#define ROT_BLOCKS (GM * NGRP / 4)             // 16384
#define DQ_BLOCKS  (GN * NGRP * 4 / 256)       // 5504

__global__ __launch_bounds__(256) void prep_kernel(
    const float* __restrict__ x, const float* __restrict__ s1,
    const float* __restrict__ s2, u32* __restrict__ rx,
    const u32* __restrict__ p32, const float* __restrict__ norms,
    u16* __restrict__ wq) {
    if (blockIdx.x < ROT_BLOCKS) {
        int gid  = blockIdx.x * 256 + threadIdx.x;
        int grp  = gid >> 6;
        int lane = gid & 63;

        const float2* xp = (const float2*)(x + (size_t)grp * GSZ);
        float2 xv  = xp[lane];
        float2 s1v = ((const float2*)s1)[lane];
        float2 s2v = ((const float2*)s2)[lane];

        float e0 = xv.x * s1v.x;
        float e1 = xv.y * s1v.y;
        {
            float a = e0 + e1, b = e0 - e1;
            e0 = a; e1 = b;
        }
        #pragma unroll
        for (int hb = 1; hb <= 32; hb <<= 1) {
            float t0 = __shfl_xor(e0, hb, 64);
            float t1 = __shfl_xor(e1, hb, 64);
            bool up = (lane & hb) != 0;
            e0 = up ? (t0 - e0) : (e0 + t0);
            e1 = up ? (t1 - e1) : (e1 + t1);
        }
        const float inv = 0.08838834764831845f;   // 1/sqrt(128)
        u32 lo = f2bf(e0 * s2v.x * inv);
        u32 hi = f2bf(e1 * s2v.y * inv);
        rx[gid] = lo | (hi << 16);
    } else {
        int u = (blockIdx.x - ROT_BLOCKS) * 256 + threadIdx.x;
        int g_idx = u >> 2;

        float scale = norms[g_idx] * 0.08838834764831845f;

        u32 w0 = p32[(size_t)u * 3 + 0];
        u32 w1 = p32[(size_t)u * 3 + 1];
        u32 w2 = p32[(size_t)u * 3 + 2];

        u32 tri[4];
        if (((w0 | w1 | w2) & 0xFFFFFF00u) == 0u) {
            const u32* pi = p32 + (size_t)u * 12;
            u32 b[12];
            #pragma unroll
            for (int k = 0; k < 12; ++k) b[k] = pi[k];
            #pragma unroll
            for (int t = 0; t < 4; ++t)
                tri[t] = b[3*t] | (b[3*t+1] << 8) | (b[3*t+2] << 16);
        } else {
            tri[0] = w0 & 0xFFFFFFu;
            tri[1] = (w0 >> 24) | ((w1 & 0xFFFFu) << 8);
            tri[2] = (w1 >> 16) | ((w2 & 0xFFu) << 16);
            tri[3] = w2 >> 8;
        }

        u32 ow[16];
        #pragma unroll
        for (int t = 0; t < 4; ++t) {
            u32 v = tri[t];
            #pragma unroll
            for (int k = 0; k < 4; ++k) {
                int i0 = (int)((v >> (6*k))     & 7u);
                int i1 = (int)((v >> (6*k + 3)) & 7u);
                u32 lo = f2bf(cent3(i0) * scale);
                u32 hi = f2bf(cent3(i1) * scale);
                ow[t*4 + k] = lo | (hi << 16);
            }
        }
        u32* op = (u32*)(wq + (size_t)u * 32);
        #pragma unroll
        for (int k = 0; k < 16; ++k) op[k] = ow[k];
    }
}

// ---------------------------------------------------------------------------
// Shared: async half-tile staging (64 rows x 64 cols bf16 per call)
// ---------------------------------------------------------------------------
__device__ __forceinline__ void stage_half(const u16* g, char* ldst, int rowOff, int tt) {
    __builtin_amdgcn_global_load_lds(CAST_G(g + (size_t)rowOff * GK + tt * 64),
                                     CAST_L(ldst), 16, 0, 0);
    __builtin_amdgcn_global_load_lds(CAST_G(g + (size_t)(rowOff + 64) * GK + tt * 64),
                                     CAST_L(ldst + 8192), 16, 0, 0);
}

// ---------------------------------------------------------------------------
// Big path: 256x256 tile, BK=64, 4 phases/K-tile, 2-deep 128 KiB LDS,
// counted vmcnt(6), T2 both-sides XOR swizzle, T5 setprio.
// EXACT r7 ktile body (phase-local reads; r8 read-ahead reverted).
// ---------------------------------------------------------------------------
template<int BUF>
__device__ __forceinline__ void ktile4(int t, char* lds,
                                       const u16* gA, const u16* gB,
                                       int sB, int aBase, int bBase, int sw0, int sw1,
                                       f32x4 (&acc)[8][4]) {
    const int AB  = BUF * 32768;
    const int BB  = 65536 + BUF * 32768;
    const int BBo = 65536 + (BUF ^ 1) * 32768;

    bf16x8 aF[4][2], b0F[2][2], b1F[2][2];
    bool s1 = (t < 63), s2 = (t < 62);

    // ---- phase 1: quadrant (mh0, nh0)
    #pragma unroll
    for (int mj = 0; mj < 4; ++mj) {
        aF[mj][0] = *(const bf16x8*)(lds + AB + aBase + mj * 4096 + sw0);
        aF[mj][1] = *(const bf16x8*)(lds + AB + aBase + mj * 4096 + sw1);
    }
    #pragma unroll
    for (int nj = 0; nj < 2; ++nj) {
        b0F[nj][0] = *(const bf16x8*)(lds + BB + bBase + nj * 8192 + sw0);
        b0F[nj][1] = *(const bf16x8*)(lds + BB + bBase + nj * 8192 + sw1);
    }
    if (s1) stage_half(gB, lds + BBo + 16384 + sB, 128, t + 1);   // (t+1) B1
    BAR(); SCHED0();
    __builtin_amdgcn_s_setprio(1);
    #pragma unroll
    for (int mj = 0; mj < 4; ++mj)
        #pragma unroll
        for (int nj = 0; nj < 2; ++nj)
            #pragma unroll
            for (int kk = 0; kk < 2; ++kk)
                acc[mj][nj] = __builtin_amdgcn_mfma_f32_16x16x32_bf16(
                    aF[mj][kk], b0F[nj][kk], acc[mj][nj], 0, 0, 0);
    __builtin_amdgcn_s_setprio(0);
    BAR();

    // ---- phase 2: (mh0, nh1)
    #pragma unroll
    for (int nj = 0; nj < 2; ++nj) {
        b1F[nj][0] = *(const bf16x8*)(lds + BB + 16384 + bBase + nj * 8192 + sw0);
        b1F[nj][1] = *(const bf16x8*)(lds + BB + 16384 + bBase + nj * 8192 + sw1);
    }
    if (s2) stage_half(gA, lds + AB + sB, 0, t + 2);              // (t+2) A0
    BAR(); SCHED0();
    __builtin_amdgcn_s_setprio(1);
    #pragma unroll
    for (int mj = 0; mj < 4; ++mj)
        #pragma unroll
        for (int nj = 0; nj < 2; ++nj)
            #pragma unroll
            for (int kk = 0; kk < 2; ++kk)
                acc[mj][2 + nj] = __builtin_amdgcn_mfma_f32_16x16x32_bf16(
                    aF[mj][kk], b1F[nj][kk], acc[mj][2 + nj], 0, 0, 0);
    __builtin_amdgcn_s_setprio(0);
    BAR();

    // ---- phase 3: (mh1, nh0)
    #pragma unroll
    for (int mj = 0; mj < 4; ++mj) {
        aF[mj][0] = *(const bf16x8*)(lds + AB + 16384 + aBase + mj * 4096 + sw0);
        aF[mj][1] = *(const bf16x8*)(lds + AB + 16384 + aBase + mj * 4096 + sw1);
    }
    if (s2) stage_half(gB, lds + BB + sB, 0, t + 2);              // (t+2) B0
    BAR(); SCHED0();
    __builtin_amdgcn_s_setprio(1);
    #pragma unroll
    for (int mj = 0; mj < 4; ++mj)
        #pragma unroll
        for (int nj = 0; nj < 2; ++nj)
            #pragma unroll
            for (int kk = 0; kk < 2; ++kk)
                acc[4 + mj][nj] = __builtin_amdgcn_mfma_f32_16x16x32_bf16(
                    aF[mj][kk], b0F[nj][kk], acc[4 + mj][nj], 0, 0, 0);
    __builtin_amdgcn_s_setprio(0);
    BAR();

    // ---- phase 4: (mh1, nh1)
    if (s2) stage_half(gA, lds + AB + 16384 + sB, 128, t + 2);    // (t+2) A1
    BAR(); SCHED0();
    __builtin_amdgcn_s_setprio(1);
    #pragma unroll
    for (int mj = 0; mj < 4; ++mj)
        #pragma unroll
        for (int nj = 0; nj < 2; ++nj)
            #pragma unroll
            for (int kk = 0; kk < 2; ++kk)
                acc[4 + mj][2 + nj] = __builtin_amdgcn_mfma_f32_16x16x32_bf16(
                    aF[mj][kk], b1F[nj][kk], acc[4 + mj][2 + nj], 0, 0, 0);
    __builtin_amdgcn_s_setprio(0);
    if (s2) { asm volatile("s_waitcnt vmcnt(6)" ::: "memory"); }
    else    { asm volatile("s_waitcnt vmcnt(0)" ::: "memory"); }
    BAR();
}

__device__ __forceinline__ void gemm_big(int tau, int tid, char* lds,
                                         const u16* A, const u16* Bw, float* C) {
    int lane = tid & 63;
    int wv   = tid >> 6;
    int wr   = wv >> 2;
    int wc   = wv & 3;

    // *** n-pinned XCD mapping ***: XCD x (= tau%8) handles n-tiles
    // {x, x+8, x+16, x+24} x all 8 m-tiles. Each B K-slice fetched ONCE
    // per XCD (L2-served 8x); A (16 MB) rides L3. L3 demand 736->218 MB.
    int n0 = (tau & 31) * 256;
    int m0 = (tau >> 5) * 256;

    int srow = tid >> 3;
    int c16  = (tid & 7) ^ (srow & 7);
    const u16* gA = A  + (size_t)(m0 + srow) * GK + c16 * 8;
    const u16* gB = Bw + (size_t)(n0 + srow) * GK + c16 * 8;
    int sB = wv * 1024;

    int aBase = (wr * 16 + (lane & 15)) * 128;
    int bBase = (wc * 16 + (lane & 15)) * 128;
    int sw0 = (((lane >> 4))     ^ (lane & 7)) << 4;
    int sw1 = (((lane >> 4) + 4) ^ (lane & 7)) << 4;

    f32x4 acc[8][4] = {};

    stage_half(gA, lds + sB,                 0,   0);
    stage_half(gB, lds + 65536 + sB,         0,   0);
    stage_half(gA, lds + 16384 + sB,         128, 0);
    stage_half(gB, lds + 65536 + 16384 + sB, 128, 0);
    stage_half(gA, lds + 32768 + sB,         0,   1);
    stage_half(gB, lds + 65536 + 32768 + sB, 0,   1);
    stage_half(gA, lds + 32768 + 16384 + sB, 128, 1);
    asm volatile("s_waitcnt vmcnt(6)" ::: "memory");
    BAR();

    for (int tt = 0; tt < 64; tt += 2) {
        ktile4<0>(tt,     lds, gA, gB, sB, aBase, bBase, sw0, sw1, acc);
        ktile4<1>(tt + 1, lds, gA, gB, sB, aBase, bBase, sw0, sw1, acc);
    }

    int cr = (lane >> 4) * 4;
    int cc = lane & 15;
    #pragma unroll
    for (int mh = 0; mh < 2; ++mh)
        #pragma unroll
        for (int mj = 0; mj < 4; ++mj)
            #pragma unroll
            for (int nh = 0; nh < 2; ++nh)
                #pragma unroll
                for (int nj = 0; nj < 2; ++nj) {
                    float* cp = C + (size_t)(m0 + mh * 128 + wr * 16 + mj * 32 + cr) * GN
                                  + (n0 + nh * 128 + wc * 16 + nj * 64 + cc);
                    #pragma unroll
                    for (int j = 0; j < 4; ++j)
                        __builtin_nontemporal_store(acc[mh * 4 + mj][nh * 2 + nj][j],
                                                    cp + (size_t)j * GN);
                }
}

// ---------------------------------------------------------------------------
// Tail path: 128x256 tile, full-K, 3-deep 144 KiB LDS, 2 phases/K-tile,
// vmcnt(6). EXACT r7 body; n-grouped XCD mapping.
// ---------------------------------------------------------------------------
template<int BUF>
__device__ __forceinline__ void ktile2(int t, char* lds,
                                       const u16* gA, const u16* gB,
                                       int sB, int aBase, int bBase, int sw0, int sw1,
                                       f32x4 (&acc)[4][4]) {
    const int AB  = BUF * 16384;
    const int BB  = 49152 + BUF * 32768;
    const int NB  = (BUF + 2 >= 3) ? (BUF - 1) : (BUF + 2);
    const int ABn = NB * 16384;
    const int BBn = 49152 + NB * 32768;

    bf16x8 aF[4][2], bF[2][2];
    bool s2 = (t < 62);

    #pragma unroll
    for (int mj = 0; mj < 4; ++mj) {
        aF[mj][0] = *(const bf16x8*)(lds + AB + aBase + mj * 4096 + sw0);
        aF[mj][1] = *(const bf16x8*)(lds + AB + aBase + mj * 4096 + sw1);
    }
    #pragma unroll
    for (int nj = 0; nj < 2; ++nj) {
        bF[nj][0] = *(const bf16x8*)(lds + BB + bBase + nj * 8192 + sw0);
        bF[nj][1] = *(const bf16x8*)(lds + BB + bBase + nj * 8192 + sw1);
    }
    if (s2) {
        stage_half(gA, lds + ABn + sB, 0, t + 2);
        stage_half(gB, lds + BBn + sB, 0, t + 2);
    }
    BAR(); SCHED0();
    __builtin_amdgcn_s_setprio(1);
    #pragma unroll
    for (int mj = 0; mj < 4; ++mj)
        #pragma unroll
        for (int nj = 0; nj < 2; ++nj)
            #pragma unroll
            for (int kk = 0; kk < 2; ++kk)
                acc[mj][nj] = __builtin_amdgcn_mfma_f32_16x16x32_bf16(
                    aF[mj][kk], bF[nj][kk], acc[mj][nj], 0, 0, 0);
    __builtin_amdgcn_s_setprio(0);
    BAR();

    #pragma unroll
    for (int nj = 0; nj < 2; ++nj) {
        bF[nj][0] = *(const bf16x8*)(lds + BB + 16384 + bBase + nj * 8192 + sw0);
        bF[nj][1] = *(const bf16x8*)(lds + BB + 16384 + bBase + nj * 8192 + sw1);
    }
    if (s2) stage_half(gB, lds + BBn + 16384 + sB, 128, t + 2);
    BAR(); SCHED0();
    __builtin_amdgcn_s_setprio(1);
    #pragma unroll
    for (int mj = 0; mj < 4; ++mj)
        #pragma unroll
        for (int nj = 0; nj < 2; ++nj)
            #pragma unroll
            for (int kk = 0; kk < 2; ++kk)
                acc[mj][2 + nj] = __builtin_amdgcn_mfma_f32_16x16x32_bf16(
                    aF[mj][kk], bF[nj][kk], acc[mj][2 + nj], 0, 0, 0);
    __builtin_amdgcn_s_setprio(0);
    if (s2) { asm volatile("s_waitcnt vmcnt(6)" ::: "memory"); }
    else    { asm volatile("s_waitcnt vmcnt(0)" ::: "memory"); }
    BAR();
}

__device__ __forceinline__ void gemm_tail(int bid, int tid, char* lds,
                                          const u16* A, const u16* Bw, float* C) {
    int lane = tid & 63;
    int wv   = tid >> 6;
    int wr   = wv >> 2;
    int wc   = wv & 3;

    // n-grouped mapping: XCD x mostly handles n-tile x (B slice L2-shared
    // by its 16 m-blocks); n-tiles 8..10 spread over the remainder.
    int x = bid & 7, s = bid >> 3;             // s in 0..21
    int nt, mh;
    if (s < 16) { nt = x; mh = s; }
    else { int idx = (s - 16) * 8 + x; nt = 8 + (idx >> 4); mh = idx & 15; }
    int m0  = mh * 128;
    int n0  = 8192 + nt * 256;

    int srow = tid >> 3;
    int c16  = (tid & 7) ^ (srow & 7);
    const u16* gA = A  + (size_t)(m0 + srow) * GK + c16 * 8;
    const u16* gB = Bw + (size_t)(n0 + srow) * GK + c16 * 8;
    int sB = wv * 1024;

    int aBase = (wr * 16 + (lane & 15)) * 128;
    int bBase = (wc * 16 + (lane & 15)) * 128;
    int sw0 = (((lane >> 4))     ^ (lane & 7)) << 4;
    int sw1 = (((lane >> 4) + 4) ^ (lane & 7)) << 4;

    f32x4 acc[4][4] = {};

    stage_half(gA, lds + sB,                 0,   0);
    stage_half(gB, lds + 49152 + sB,         0,   0);
    stage_half(gB, lds + 49152 + 16384 + sB, 128, 0);
    stage_half(gA, lds + 16384 + sB,         0,   1);
    stage_half(gB, lds + 81920 + sB,         0,   1);
    stage_half(gB, lds + 81920 + 16384 + sB, 128, 1);
    asm volatile("s_waitcnt vmcnt(6)" ::: "memory");
    BAR();

    for (int tt = 0; tt < 63; tt += 3) {
        ktile2<0>(tt,     lds, gA, gB, sB, aBase, bBase, sw0, sw1, acc);
        ktile2<1>(tt + 1, lds, gA, gB, sB, aBase, bBase, sw0, sw1, acc);
        ktile2<2>(tt + 2, lds, gA, gB, sB, aBase, bBase, sw0, sw1, acc);
    }
    ktile2<0>(63, lds, gA, gB, sB, aBase, bBase, sw0, sw1, acc);

    int cr = (lane >> 4) * 4;
    int cc = lane & 15;
    #pragma unroll
    for (int mj = 0; mj < 4; ++mj)
        #pragma unroll
        for (int nj = 0; nj < 4; ++nj) {
            float* cp = C + (size_t)(m0 + wr * 16 + mj * 32 + cr) * GN
                          + (n0 + wc * 16 + nj * 64 + cc);
            #pragma unroll
            for (int j = 0; j < 4; ++j)
                __builtin_nontemporal_store(acc[mj][nj][j], cp + (size_t)j * GN);
        }
}

// ---------------------------------------------------------------------------
// Merged GEMM: 432 blocks. 0..255 = 256x256 full tiles (n < 8192),
// 256..431 = 128x256 full-K tail tiles (n >= 8192). LPT order.
// ---------------------------------------------------------------------------
__global__ __launch_bounds__(512, 1) void gemm_all_kernel(
    const u16* __restrict__ A, const u16* __restrict__ Bw,
    float* __restrict__ C) {
    extern __shared__ char lds[];
    int bid = blockIdx.x;
    if (bid < 256) gemm_big (bid,       threadIdx.x, lds, A, Bw, C);
    else           gemm_tail(bid - 256, threadIdx.x, lds, A, Bw, C);
}

// ---------------------------------------------------------------------------
extern "C" void kernel_launch(void* const* d_in, const int* in_sizes, int n_in,
                              void* d_out, int out_size, void* d_ws, size_t ws_size,
                              hipStream_t stream) {
    const float* x      = (const float*)d_in[0];
    const void*  packed = d_in[1];
    const float* norms  = (const float*)d_in[2];
    const float* s1     = (const float*)d_in[4];
    const float* s2     = (const float*)d_in[5];
    float* out          = (float*)d_out;

    size_t rx_bytes = (size_t)GM * GK * 2;
    size_t wq_bytes = (size_t)GN * GK * 2;
    if (ws_size < rx_bytes + wq_bytes) return;

    u16* rx = (u16*)d_ws;
    u16* wq = rx + (size_t)GM * GK;

    prep_kernel<<<dim3(ROT_BLOCKS + DQ_BLOCKS), dim3(256), 0, stream>>>(
        x, s1, s2, (u32*)rx, (const u32*)packed, norms, wq);

    hipFuncSetAttribute((const void*)gemm_all_kernel,
                        hipFuncAttributeMaxDynamicSharedMemorySize, 147456);
    gemm_all_kernel<<<dim3(432), dim3(512), 147456, stream>>>(rx, wq, out);
}

// Round 10
// 208.168 us; speedup vs baseline: 1.0645x; 1.0272x over previous
//
#include <hip/hip_runtime.h>

typedef unsigned int u32;
typedef unsigned short u16;

typedef short bf16x8 __attribute__((ext_vector_type(8)));
typedef float f32x4 __attribute__((ext_vector_type(4)));

#define GM 2048      // B
#define GN 11008     // O
#define GK 4096      // I
#define NGRP 32      // N = I/G
#define GSZ 128      // G

#define CAST_G(p) ((const __attribute__((address_space(1))) void*)(p))
#define CAST_L(p) ((__attribute__((address_space(3))) void*)(p))
#define BAR() __builtin_amdgcn_s_barrier()
#define SCHED0() __builtin_amdgcn_sched_barrier(0)

__device__ __forceinline__ u16 f2bf(float f) {
    u32 u = __builtin_bit_cast(u32, f);
    u32 r = (u + 0x7FFFu + ((u >> 16) & 1u)) >> 16;
    return (u16)r;
}

// ---------------------------------------------------------------------------
// Prep (merged): rotate x -> rx (bf16) AND dequant packed 3-bit -> wq bf16.
// ~21.6 us measured (r8) at the 156 MB traffic roofline.
// ---------------------------------------------------------------------------
__device__ __forceinline__ float cent3(int i) {
    int m3 = (i >= 4) ? (i - 4) : (3 - i);
    float mag = (m3 >= 2) ? ((m3 == 3) ? 2.1519f : 1.3439f)
                          : ((m3 == 1) ? 0.756f  : 0.2451f);
    return (i >= 4) ? mag : -mag;
}

#define ROT_BLOCKS (GM * NGRP / 4)             // 16384
#define DQ_BLOCKS  (GN * NGRP * 4 / 256)       // 5504

__global__ __launch_bounds__(256) void prep_kernel(
    const float* __restrict__ x, const float* __restrict__ s1,
    const float* __restrict__ s2, u32* __restrict__ rx,
    const u32* __restrict__ p32, const float* __restrict__ norms,
    u16* __restrict__ wq) {
    if (blockIdx.x < ROT_BLOCKS) {
        int gid  = blockIdx.x * 256 + threadIdx.x;
        int grp  = gid >> 6;
        int lane = gid & 63;

        const float2* xp = (const float2*)(x + (size_t)grp * GSZ);
        float2 xv  = xp[lane];
        float2 s1v = ((const float2*)s1)[lane];
        float2 s2v = ((const float2*)s2)[lane];

        float e0 = xv.x * s1v.x;
        float e1 = xv.y * s1v.y;
        {
            float a = e0 + e1, b = e0 - e1;
            e0 = a; e1 = b;
        }
        #pragma unroll
        for (int hb = 1; hb <= 32; hb <<= 1) {
            float t0 = __shfl_xor(e0, hb, 64);
            float t1 = __shfl_xor(e1, hb, 64);
            bool up = (lane & hb) != 0;
            e0 = up ? (t0 - e0) : (e0 + t0);
            e1 = up ? (t1 - e1) : (e1 + t1);
        }
        const float inv = 0.08838834764831845f;   // 1/sqrt(128)
        u32 lo = f2bf(e0 * s2v.x * inv);
        u32 hi = f2bf(e1 * s2v.y * inv);
        rx[gid] = lo | (hi << 16);
    } else {
        int u = (blockIdx.x - ROT_BLOCKS) * 256 + threadIdx.x;
        int g_idx = u >> 2;

        float scale = norms[g_idx] * 0.08838834764831845f;

        u32 w0 = p32[(size_t)u * 3 + 0];
        u32 w1 = p32[(size_t)u * 3 + 1];
        u32 w2 = p32[(size_t)u * 3 + 2];

        u32 tri[4];
        if (((w0 | w1 | w2) & 0xFFFFFF00u) == 0u) {
            const u32* pi = p32 + (size_t)u * 12;
            u32 b[12];
            #pragma unroll
            for (int k = 0; k < 12; ++k) b[k] = pi[k];
            #pragma unroll
            for (int t = 0; t < 4; ++t)
                tri[t] = b[3*t] | (b[3*t+1] << 8) | (b[3*t+2] << 16);
        } else {
            tri[0] = w0 & 0xFFFFFFu;
            tri[1] = (w0 >> 24) | ((w1 & 0xFFFFu) << 8);
            tri[2] = (w1 >> 16) | ((w2 & 0xFFu) << 16);
            tri[3] = w2 >> 8;
        }

        u32 ow[16];
        #pragma unroll
        for (int t = 0; t < 4; ++t) {
            u32 v = tri[t];
            #pragma unroll
            for (int k = 0; k < 4; ++k) {
                int i0 = (int)((v >> (6*k))     & 7u);
                int i1 = (int)((v >> (6*k + 3)) & 7u);
                u32 lo = f2bf(cent3(i0) * scale);
                u32 hi = f2bf(cent3(i1) * scale);
                ow[t*4 + k] = lo | (hi << 16);
            }
        }
        u32* op = (u32*)(wq + (size_t)u * 32);
        #pragma unroll
        for (int k = 0; k < 16; ++k) op[k] = ow[k];
    }
}

// ---------------------------------------------------------------------------
// Shared: async half-tile staging (64 rows x 64 cols bf16 per call)
// ---------------------------------------------------------------------------
__device__ __forceinline__ void stage_half(const u16* g, char* ldst, int rowOff, int tt) {
    __builtin_amdgcn_global_load_lds(CAST_G(g + (size_t)rowOff * GK + tt * 64),
                                     CAST_L(ldst), 16, 0, 0);
    __builtin_amdgcn_global_load_lds(CAST_G(g + (size_t)(rowOff + 64) * GK + tt * 64),
                                     CAST_L(ldst + 8192), 16, 0, 0);
}

// ---------------------------------------------------------------------------
// Big path: 256x256 tile, BK=64, 4 phases/K-tile, 2-deep 128 KiB LDS,
// counted vmcnt(6), T2 both-sides XOR swizzle, T5 setprio.
// r10 change: SINGLE barrier per phase (end only). Hazard invariant: each
// region's reads complete (lgkmcnt before own MFMA) < end-BAR(P) <
// restage-issue (P+1). Pre-MFMA barrier dropped -> waves drift within a
// phase: one wave MFMAs while another reads (MFMA/LDS pipes overlap).
// ---------------------------------------------------------------------------
template<int BUF>
__device__ __forceinline__ void ktile4(int t, char* lds,
                                       const u16* gA, const u16* gB,
                                       int sB, int aBase, int bBase, int sw0, int sw1,
                                       f32x4 (&acc)[8][4]) {
    const int AB  = BUF * 32768;
    const int BB  = 65536 + BUF * 32768;
    const int BBo = 65536 + (BUF ^ 1) * 32768;

    bf16x8 aF[4][2], b0F[2][2], b1F[2][2];
    bool s1 = (t < 63), s2 = (t < 62);

    // ---- phase 1: reads aF(mh0)+b0F; stage B1(t+1)->other; MFMA (mh0,nh0)
    #pragma unroll
    for (int mj = 0; mj < 4; ++mj) {
        aF[mj][0] = *(const bf16x8*)(lds + AB + aBase + mj * 4096 + sw0);
        aF[mj][1] = *(const bf16x8*)(lds + AB + aBase + mj * 4096 + sw1);
    }
    #pragma unroll
    for (int nj = 0; nj < 2; ++nj) {
        b0F[nj][0] = *(const bf16x8*)(lds + BB + bBase + nj * 8192 + sw0);
        b0F[nj][1] = *(const bf16x8*)(lds + BB + bBase + nj * 8192 + sw1);
    }
    if (s1) stage_half(gB, lds + BBo + 16384 + sB, 128, t + 1);
    SCHED0();
    __builtin_amdgcn_s_setprio(1);
    #pragma unroll
    for (int mj = 0; mj < 4; ++mj)
        #pragma unroll
        for (int nj = 0; nj < 2; ++nj)
            #pragma unroll
            for (int kk = 0; kk < 2; ++kk)
                acc[mj][nj] = __builtin_amdgcn_mfma_f32_16x16x32_bf16(
                    aF[mj][kk], b0F[nj][kk], acc[mj][nj], 0, 0, 0);
    __builtin_amdgcn_s_setprio(0);
    BAR();

    // ---- phase 2: reads b1F; stage A0(t+2)->this; MFMA (mh0,nh1)
    #pragma unroll
    for (int nj = 0; nj < 2; ++nj) {
        b1F[nj][0] = *(const bf16x8*)(lds + BB + 16384 + bBase + nj * 8192 + sw0);
        b1F[nj][1] = *(const bf16x8*)(lds + BB + 16384 + bBase + nj * 8192 + sw1);
    }
    if (s2) stage_half(gA, lds + AB + sB, 0, t + 2);
    SCHED0();
    __builtin_amdgcn_s_setprio(1);
    #pragma unroll
    for (int mj = 0; mj < 4; ++mj)
        #pragma unroll
        for (int nj = 0; nj < 2; ++nj)
            #pragma unroll
            for (int kk = 0; kk < 2; ++kk)
                acc[mj][2 + nj] = __builtin_amdgcn_mfma_f32_16x16x32_bf16(
                    aF[mj][kk], b1F[nj][kk], acc[mj][2 + nj], 0, 0, 0);
    __builtin_amdgcn_s_setprio(0);
    BAR();

    // ---- phase 3: reads aF(mh1); stage B0(t+2)->this; MFMA (mh1,nh0)
    #pragma unroll
    for (int mj = 0; mj < 4; ++mj) {
        aF[mj][0] = *(const bf16x8*)(lds + AB + 16384 + aBase + mj * 4096 + sw0);
        aF[mj][1] = *(const bf16x8*)(lds + AB + 16384 + aBase + mj * 4096 + sw1);
    }
    if (s2) stage_half(gB, lds + BB + sB, 0, t + 2);
    SCHED0();
    __builtin_amdgcn_s_setprio(1);
    #pragma unroll
    for (int mj = 0; mj < 4; ++mj)
        #pragma unroll
        for (int nj = 0; nj < 2; ++nj)
            #pragma unroll
            for (int kk = 0; kk < 2; ++kk)
                acc[4 + mj][nj] = __builtin_amdgcn_mfma_f32_16x16x32_bf16(
                    aF[mj][kk], b0F[nj][kk], acc[4 + mj][nj], 0, 0, 0);
    __builtin_amdgcn_s_setprio(0);
    BAR();

    // ---- phase 4: stage A1(t+2)->this; MFMA (mh1,nh1); vmcnt(6)
    if (s2) stage_half(gA, lds + AB + 16384 + sB, 128, t + 2);
    SCHED0();
    __builtin_amdgcn_s_setprio(1);
    #pragma unroll
    for (int mj = 0; mj < 4; ++mj)
        #pragma unroll
        for (int nj = 0; nj < 2; ++nj)
            #pragma unroll
            for (int kk = 0; kk < 2; ++kk)
                acc[4 + mj][2 + nj] = __builtin_amdgcn_mfma_f32_16x16x32_bf16(
                    aF[mj][kk], b1F[nj][kk], acc[4 + mj][2 + nj], 0, 0, 0);
    __builtin_amdgcn_s_setprio(0);
    if (s2) { asm volatile("s_waitcnt vmcnt(6)" ::: "memory"); }
    else    { asm volatile("s_waitcnt vmcnt(0)" ::: "memory"); }
    BAR();
}

__device__ __forceinline__ void gemm_big(int tau, int tid, char* lds,
                                         const u16* A, const u16* Bw, float* C) {
    int lane = tid & 63;
    int wv   = tid >> 6;
    int wr   = wv >> 2;
    int wc   = wv & 3;

    // n-pinned XCD mapping: XCD x handles n-tiles {x, x+8, x+16, x+24} x all
    // m-tiles; each B K-slice fetched once per XCD (L2-served 8x).
    int n0 = (tau & 31) * 256;
    int m0 = (tau >> 5) * 256;

    int srow = tid >> 3;
    int c16  = (tid & 7) ^ (srow & 7);
    const u16* gA = A  + (size_t)(m0 + srow) * GK + c16 * 8;
    const u16* gB = Bw + (size_t)(n0 + srow) * GK + c16 * 8;
    int sB = wv * 1024;

    int aBase = (wr * 16 + (lane & 15)) * 128;
    int bBase = (wc * 16 + (lane & 15)) * 128;
    int sw0 = (((lane >> 4))     ^ (lane & 7)) << 4;
    int sw1 = (((lane >> 4) + 4) ^ (lane & 7)) << 4;

    f32x4 acc[8][4] = {};

    stage_half(gA, lds + sB,                 0,   0);
    stage_half(gB, lds + 65536 + sB,         0,   0);
    stage_half(gA, lds + 16384 + sB,         128, 0);
    stage_half(gB, lds + 65536 + 16384 + sB, 128, 0);
    stage_half(gA, lds + 32768 + sB,         0,   1);
    stage_half(gB, lds + 65536 + 32768 + sB, 0,   1);
    stage_half(gA, lds + 32768 + 16384 + sB, 128, 1);
    asm volatile("s_waitcnt vmcnt(6)" ::: "memory");
    BAR();

    for (int tt = 0; tt < 64; tt += 2) {
        ktile4<0>(tt,     lds, gA, gB, sB, aBase, bBase, sw0, sw1, acc);
        ktile4<1>(tt + 1, lds, gA, gB, sB, aBase, bBase, sw0, sw1, acc);
    }

    int cr = (lane >> 4) * 4;
    int cc = lane & 15;
    #pragma unroll
    for (int mh = 0; mh < 2; ++mh)
        #pragma unroll
        for (int mj = 0; mj < 4; ++mj)
            #pragma unroll
            for (int nh = 0; nh < 2; ++nh)
                #pragma unroll
                for (int nj = 0; nj < 2; ++nj) {
                    float* cp = C + (size_t)(m0 + mh * 128 + wr * 16 + mj * 32 + cr) * GN
                                  + (n0 + nh * 128 + wc * 16 + nj * 64 + cc);
                    #pragma unroll
                    for (int j = 0; j < 4; ++j)
                        __builtin_nontemporal_store(acc[mh * 4 + mj][nh * 2 + nj][j],
                                                    cp + (size_t)j * GN);
                }
}

// ---------------------------------------------------------------------------
// Tail path: 128x256 tile, full-K, 3-deep 144 KiB LDS, 2 phases/K-tile,
// vmcnt(6); single end-of-phase barrier (same invariant as big path).
// ---------------------------------------------------------------------------
template<int BUF>
__device__ __forceinline__ void ktile2(int t, char* lds,
                                       const u16* gA, const u16* gB,
                                       int sB, int aBase, int bBase, int sw0, int sw1,
                                       f32x4 (&acc)[4][4]) {
    const int AB  = BUF * 16384;
    const int BB  = 49152 + BUF * 32768;
    const int NB  = (BUF + 2 >= 3) ? (BUF - 1) : (BUF + 2);
    const int ABn = NB * 16384;
    const int BBn = 49152 + NB * 32768;

    bf16x8 aF[4][2], bF[2][2];
    bool s2 = (t < 62);

    // ---- phase 1: reads aF+b0F; stage A(t+2),B0(t+2); MFMA nj0,1
    #pragma unroll
    for (int mj = 0; mj < 4; ++mj) {
        aF[mj][0] = *(const bf16x8*)(lds + AB + aBase + mj * 4096 + sw0);
        aF[mj][1] = *(const bf16x8*)(lds + AB + aBase + mj * 4096 + sw1);
    }
    #pragma unroll
    for (int nj = 0; nj < 2; ++nj) {
        bF[nj][0] = *(const bf16x8*)(lds + BB + bBase + nj * 8192 + sw0);
        bF[nj][1] = *(const bf16x8*)(lds + BB + bBase + nj * 8192 + sw1);
    }
    if (s2) {
        stage_half(gA, lds + ABn + sB, 0, t + 2);
        stage_half(gB, lds + BBn + sB, 0, t + 2);
    }
    SCHED0();
    __builtin_amdgcn_s_setprio(1);
    #pragma unroll
    for (int mj = 0; mj < 4; ++mj)
        #pragma unroll
        for (int nj = 0; nj < 2; ++nj)
            #pragma unroll
            for (int kk = 0; kk < 2; ++kk)
                acc[mj][nj] = __builtin_amdgcn_mfma_f32_16x16x32_bf16(
                    aF[mj][kk], bF[nj][kk], acc[mj][nj], 0, 0, 0);
    __builtin_amdgcn_s_setprio(0);
    BAR();

    // ---- phase 2: reads b1F; stage B1(t+2); MFMA nj2,3; vmcnt(6)
    #pragma unroll
    for (int nj = 0; nj < 2; ++nj) {
        bF[nj][0] = *(const bf16x8*)(lds + BB + 16384 + bBase + nj * 8192 + sw0);
        bF[nj][1] = *(const bf16x8*)(lds + BB + 16384 + bBase + nj * 8192 + sw1);
    }
    if (s2) stage_half(gB, lds + BBn + 16384 + sB, 128, t + 2);
    SCHED0();
    __builtin_amdgcn_s_setprio(1);
    #pragma unroll
    for (int mj = 0; mj < 4; ++mj)
        #pragma unroll
        for (int nj = 0; nj < 2; ++nj)
            #pragma unroll
            for (int kk = 0; kk < 2; ++kk)
                acc[mj][2 + nj] = __builtin_amdgcn_mfma_f32_16x16x32_bf16(
                    aF[mj][kk], bF[nj][kk], acc[mj][2 + nj], 0, 0, 0);
    __builtin_amdgcn_s_setprio(0);
    if (s2) { asm volatile("s_waitcnt vmcnt(6)" ::: "memory"); }
    else    { asm volatile("s_waitcnt vmcnt(0)" ::: "memory"); }
    BAR();
}

__device__ __forceinline__ void gemm_tail(int bid, int tid, char* lds,
                                          const u16* A, const u16* Bw, float* C) {
    int lane = tid & 63;
    int wv   = tid >> 6;
    int wr   = wv >> 2;
    int wc   = wv & 3;

    // n-grouped mapping: XCD x mostly handles n-tile x (B slice L2-shared)
    int x = bid & 7, s = bid >> 3;             // s in 0..21
    int nt, mh;
    if (s < 16) { nt = x; mh = s; }
    else { int idx = (s - 16) * 8 + x; nt = 8 + (idx >> 4); mh = idx & 15; }
    int m0  = mh * 128;
    int n0  = 8192 + nt * 256;

    int srow = tid >> 3;
    int c16  = (tid & 7) ^ (srow & 7);
    const u16* gA = A  + (size_t)(m0 + srow) * GK + c16 * 8;
    const u16* gB = Bw + (size_t)(n0 + srow) * GK + c16 * 8;
    int sB = wv * 1024;

    int aBase = (wr * 16 + (lane & 15)) * 128;
    int bBase = (wc * 16 + (lane & 15)) * 128;
    int sw0 = (((lane >> 4))     ^ (lane & 7)) << 4;
    int sw1 = (((lane >> 4) + 4) ^ (lane & 7)) << 4;

    f32x4 acc[4][4] = {};

    stage_half(gA, lds + sB,                 0,   0);
    stage_half(gB, lds + 49152 + sB,         0,   0);
    stage_half(gB, lds + 49152 + 16384 + sB, 128, 0);
    stage_half(gA, lds + 16384 + sB,         0,   1);
    stage_half(gB, lds + 81920 + sB,         0,   1);
    stage_half(gB, lds + 81920 + 16384 + sB, 128, 1);
    asm volatile("s_waitcnt vmcnt(6)" ::: "memory");
    BAR();

    for (int tt = 0; tt < 63; tt += 3) {
        ktile2<0>(tt,     lds, gA, gB, sB, aBase, bBase, sw0, sw1, acc);
        ktile2<1>(tt + 1, lds, gA, gB, sB, aBase, bBase, sw0, sw1, acc);
        ktile2<2>(tt + 2, lds, gA, gB, sB, aBase, bBase, sw0, sw1, acc);
    }
    ktile2<0>(63, lds, gA, gB, sB, aBase, bBase, sw0, sw1, acc);

    int cr = (lane >> 4) * 4;
    int cc = lane & 15;
    #pragma unroll
    for (int mj = 0; mj < 4; ++mj)
        #pragma unroll
        for (int nj = 0; nj < 4; ++nj) {
            float* cp = C + (size_t)(m0 + wr * 16 + mj * 32 + cr) * GN
                          + (n0 + wc * 16 + nj * 64 + cc);
            #pragma unroll
            for (int j = 0; j < 4; ++j)
                __builtin_nontemporal_store(acc[mj][nj][j], cp + (size_t)j * GN);
        }
}

// ---------------------------------------------------------------------------
// Merged GEMM: 432 blocks. 0..255 = 256x256 full tiles (n < 8192),
// 256..431 = 128x256 full-K tail tiles (n >= 8192). LPT order.
// ---------------------------------------------------------------------------
__global__ __launch_bounds__(512, 1) void gemm_all_kernel(
    const u16* __restrict__ A, const u16* __restrict__ Bw,
    float* __restrict__ C) {
    extern __shared__ char lds[];
    int bid = blockIdx.x;
    if (bid < 256) gemm_big (bid,       threadIdx.x, lds, A, Bw, C);
    else           gemm_tail(bid - 256, threadIdx.x, lds, A, Bw, C);
}

// ---------------------------------------------------------------------------
extern "C" void kernel_launch(void* const* d_in, const int* in_sizes, int n_in,
                              void* d_out, int out_size, void* d_ws, size_t ws_size,
                              hipStream_t stream) {
    const float* x      = (const float*)d_in[0];
    const void*  packed = d_in[1];
    const float* norms  = (const float*)d_in[2];
    const float* s1     = (const float*)d_in[4];
    const float* s2     = (const float*)d_in[5];
    float* out          = (float*)d_out;

    size_t rx_bytes = (size_t)GM * GK * 2;
    size_t wq_bytes = (size_t)GN * GK * 2;
    if (ws_size < rx_bytes + wq_bytes) return;

    u16* rx = (u16*)d_ws;
    u16* wq = rx + (size_t)GM * GK;

    prep_kernel<<<dim3(ROT_BLOCKS + DQ_BLOCKS), dim3(256), 0, stream>>>(
        x, s1, s2, (u32*)rx, (const u32*)packed, norms, wq);

    hipFuncSetAttribute((const void*)gemm_all_kernel,
                        hipFuncAttributeMaxDynamicSharedMemorySize, 147456);
    gemm_all_kernel<<<dim3(432), dim3(512), 147456, stream>>>(rx, wq, out);
}

// Round 11
// 206.970 us; speedup vs baseline: 1.0707x; 1.0058x over previous
//
#include <hip/hip_runtime.h>

typedef unsigned int u32;
typedef unsigned short u16;

typedef short bf16x8 __attribute__((ext_vector_type(8)));
typedef float f32x4 __attribute__((ext_vector_type(4)));

#define GM 2048      // B
#define GN 11008     // O
#define GK 4096      // I
#define NGRP 32      // N = I/G
#define GSZ 128      // G

#define CAST_G(p) ((const __attribute__((address_space(1))) void*)(p))
#define CAST_L(p) ((__attribute__((address_space(3))) void*)(p))
#define BAR() __builtin_amdgcn_s_barrier()
#define SCHED0() __builtin_amdgcn_sched_barrier(0)

__device__ __forceinline__ u16 f2bf(float f) {
    u32 u = __builtin_bit_cast(u32, f);
    u32 r = (u + 0x7FFFu + ((u >> 16) & 1u)) >> 16;
    return (u16)r;
}

// ---------------------------------------------------------------------------
// Prep (merged): rotate x -> rx (bf16) AND dequant packed 3-bit -> wq bf16.
// ~21.6 us measured at the 156 MB traffic roofline. (unchanged)
// ---------------------------------------------------------------------------
__device__ __forceinline__ float cent3(int i) {
    int m3 = (i >= 4) ? (i - 4) : (3 - i);
    float mag = (m3 >= 2) ? ((m3 == 3) ? 2.1519f : 1.3439f)
                          : ((m3 == 1) ? 0.756f  : 0.2451f);
    return (i >= 4) ? mag : -mag;
}

#define ROT_BLOCKS (GM * NGRP / 4)             // 16384
#define DQ_BLOCKS  (GN * NGRP * 4 / 256)       // 5504

__global__ __launch_bounds__(256) void prep_kernel(
    const float* __restrict__ x, const float* __restrict__ s1,
    const float* __restrict__ s2, u32* __restrict__ rx,
    const u32* __restrict__ p32, const float* __restrict__ norms,
    u16* __restrict__ wq) {
    if (blockIdx.x < ROT_BLOCKS) {
        int gid  = blockIdx.x * 256 + threadIdx.x;
        int grp  = gid >> 6;
        int lane = gid & 63;

        const float2* xp = (const float2*)(x + (size_t)grp * GSZ);
        float2 xv  = xp[lane];
        float2 s1v = ((const float2*)s1)[lane];
        float2 s2v = ((const float2*)s2)[lane];

        float e0 = xv.x * s1v.x;
        float e1 = xv.y * s1v.y;
        {
            float a = e0 + e1, b = e0 - e1;
            e0 = a; e1 = b;
        }
        #pragma unroll
        for (int hb = 1; hb <= 32; hb <<= 1) {
            float t0 = __shfl_xor(e0, hb, 64);
            float t1 = __shfl_xor(e1, hb, 64);
            bool up = (lane & hb) != 0;
            e0 = up ? (t0 - e0) : (e0 + t0);
            e1 = up ? (t1 - e1) : (e1 + t1);
        }
        const float inv = 0.08838834764831845f;   // 1/sqrt(128)
        u32 lo = f2bf(e0 * s2v.x * inv);
        u32 hi = f2bf(e1 * s2v.y * inv);
        rx[gid] = lo | (hi << 16);
    } else {
        int u = (blockIdx.x - ROT_BLOCKS) * 256 + threadIdx.x;
        int g_idx = u >> 2;

        float scale = norms[g_idx] * 0.08838834764831845f;

        u32 w0 = p32[(size_t)u * 3 + 0];
        u32 w1 = p32[(size_t)u * 3 + 1];
        u32 w2 = p32[(size_t)u * 3 + 2];

        u32 tri[4];
        if (((w0 | w1 | w2) & 0xFFFFFF00u) == 0u) {
            const u32* pi = p32 + (size_t)u * 12;
            u32 b[12];
            #pragma unroll
            for (int k = 0; k < 12; ++k) b[k] = pi[k];
            #pragma unroll
            for (int t = 0; t < 4; ++t)
                tri[t] = b[3*t] | (b[3*t+1] << 8) | (b[3*t+2] << 16);
        } else {
            tri[0] = w0 & 0xFFFFFFu;
            tri[1] = (w0 >> 24) | ((w1 & 0xFFFFu) << 8);
            tri[2] = (w1 >> 16) | ((w2 & 0xFFu) << 16);
            tri[3] = w2 >> 8;
        }

        u32 ow[16];
        #pragma unroll
        for (int t = 0; t < 4; ++t) {
            u32 v = tri[t];
            #pragma unroll
            for (int k = 0; k < 4; ++k) {
                int i0 = (int)((v >> (6*k))     & 7u);
                int i1 = (int)((v >> (6*k + 3)) & 7u);
                u32 lo = f2bf(cent3(i0) * scale);
                u32 hi = f2bf(cent3(i1) * scale);
                ow[t*4 + k] = lo | (hi << 16);
            }
        }
        u32* op = (u32*)(wq + (size_t)u * 32);
        #pragma unroll
        for (int k = 0; k < 16; ++k) op[k] = ow[k];
    }
}

// ---------------------------------------------------------------------------
// Shared: async half-tile staging (64 rows x 64 cols bf16 per call)
// ---------------------------------------------------------------------------
__device__ __forceinline__ void stage_half(const u16* g, char* ldst, int rowOff, int tt) {
    __builtin_amdgcn_global_load_lds(CAST_G(g + (size_t)rowOff * GK + tt * 64),
                                     CAST_L(ldst), 16, 0, 0);
    __builtin_amdgcn_global_load_lds(CAST_G(g + (size_t)(rowOff + 64) * GK + tt * 64),
                                     CAST_L(ldst + 8192), 16, 0, 0);
}

// ---------------------------------------------------------------------------
// Big path: 256x256 tile, BK=64, **2 phases/K-tile**, 2-deep 128 KiB LDS,
// single vmcnt(6)/tile, T2 both-sides XOR swizzle, T5 setprio.
// Ph1: reads aF0+b0F+b1F (16) | stage A1(t+1)->other | 32 MFMA (mh0,*) | BAR
// Ph2: reads aF1 (8) | stage A0,B0,B1(t+2)->this | 32 MFMA (mh1,*) |
//      vmcnt(6) | BAR
// Hazards: A0/B0/B1 read Ph1, restaged Ph2 (1 bar); A1 read Ph2(t),
// restaged Ph1(t+1) (1 bar). vmcnt trace: 6 at tile start -> 8 -> 14 ->
// vmcnt(6) completes b(t-1) [Ph1(t+1) reads] and a(t) [Ph2(t+1) reads].
// ---------------------------------------------------------------------------
template<int BUF>
__device__ __forceinline__ void ktile4(int t, char* lds,
                                       const u16* gA, const u16* gB,
                                       int sB, int aBase, int bBase, int sw0, int sw1,
                                       f32x4 (&acc)[8][4]) {
    const int AB  = BUF * 32768;
    const int ABo = (BUF ^ 1) * 32768;
    const int BB  = 65536 + BUF * 32768;

    bf16x8 aF[4][2], b0F[2][2], b1F[2][2];
    bool s1 = (t < 63), s2 = (t < 62);

    // ---- Phase 1: mh0 x {nh0, nh1}
    #pragma unroll
    for (int mj = 0; mj < 4; ++mj) {
        aF[mj][0] = *(const bf16x8*)(lds + AB + aBase + mj * 4096 + sw0);
        aF[mj][1] = *(const bf16x8*)(lds + AB + aBase + mj * 4096 + sw1);
    }
    #pragma unroll
    for (int nj = 0; nj < 2; ++nj) {
        b0F[nj][0] = *(const bf16x8*)(lds + BB + bBase + nj * 8192 + sw0);
        b0F[nj][1] = *(const bf16x8*)(lds + BB + bBase + nj * 8192 + sw1);
    }
    #pragma unroll
    for (int nj = 0; nj < 2; ++nj) {
        b1F[nj][0] = *(const bf16x8*)(lds + BB + 16384 + bBase + nj * 8192 + sw0);
        b1F[nj][1] = *(const bf16x8*)(lds + BB + 16384 + bBase + nj * 8192 + sw1);
    }
    if (s1) stage_half(gA, lds + ABo + 16384 + sB, 128, t + 1);   // A1(t+1)
    SCHED0();
    __builtin_amdgcn_s_setprio(1);
    #pragma unroll
    for (int mj = 0; mj < 4; ++mj)
        #pragma unroll
        for (int nj = 0; nj < 2; ++nj)
            #pragma unroll
            for (int kk = 0; kk < 2; ++kk)
                acc[mj][nj] = __builtin_amdgcn_mfma_f32_16x16x32_bf16(
                    aF[mj][kk], b0F[nj][kk], acc[mj][nj], 0, 0, 0);
    #pragma unroll
    for (int mj = 0; mj < 4; ++mj)
        #pragma unroll
        for (int nj = 0; nj < 2; ++nj)
            #pragma unroll
            for (int kk = 0; kk < 2; ++kk)
                acc[mj][2 + nj] = __builtin_amdgcn_mfma_f32_16x16x32_bf16(
                    aF[mj][kk], b1F[nj][kk], acc[mj][2 + nj], 0, 0, 0);
    __builtin_amdgcn_s_setprio(0);
    BAR();

    // ---- Phase 2: mh1 x {nh0, nh1}
    #pragma unroll
    for (int mj = 0; mj < 4; ++mj) {
        aF[mj][0] = *(const bf16x8*)(lds + AB + 16384 + aBase + mj * 4096 + sw0);
        aF[mj][1] = *(const bf16x8*)(lds + AB + 16384 + aBase + mj * 4096 + sw1);
    }
    if (s2) {
        stage_half(gA, lds + AB + sB,         0,   t + 2);        // A0(t+2)
        stage_half(gB, lds + BB + sB,         0,   t + 2);        // B0(t+2)
        stage_half(gB, lds + BB + 16384 + sB, 128, t + 2);        // B1(t+2)
    }
    SCHED0();
    __builtin_amdgcn_s_setprio(1);
    #pragma unroll
    for (int mj = 0; mj < 4; ++mj)
        #pragma unroll
        for (int nj = 0; nj < 2; ++nj)
            #pragma unroll
            for (int kk = 0; kk < 2; ++kk)
                acc[4 + mj][nj] = __builtin_amdgcn_mfma_f32_16x16x32_bf16(
                    aF[mj][kk], b0F[nj][kk], acc[4 + mj][nj], 0, 0, 0);
    #pragma unroll
    for (int mj = 0; mj < 4; ++mj)
        #pragma unroll
        for (int nj = 0; nj < 2; ++nj)
            #pragma unroll
            for (int kk = 0; kk < 2; ++kk)
                acc[4 + mj][2 + nj] = __builtin_amdgcn_mfma_f32_16x16x32_bf16(
                    aF[mj][kk], b1F[nj][kk], acc[4 + mj][2 + nj], 0, 0, 0);
    __builtin_amdgcn_s_setprio(0);
    if (s2) { asm volatile("s_waitcnt vmcnt(6)" ::: "memory"); }
    else    { asm volatile("s_waitcnt vmcnt(0)" ::: "memory"); }
    BAR();
}

__device__ __forceinline__ void gemm_big(int tau, int tid, char* lds,
                                         const u16* A, const u16* Bw, float* C) {
    int lane = tid & 63;
    int wv   = tid >> 6;
    int wr   = wv >> 2;
    int wc   = wv & 3;

    // n-pinned XCD mapping: XCD x handles n-tiles {x, x+8, x+16, x+24} x all
    // m-tiles; each B K-slice fetched once per XCD (L2-served 8x).
    int n0 = (tau & 31) * 256;
    int m0 = (tau >> 5) * 256;

    int srow = tid >> 3;
    int c16  = (tid & 7) ^ (srow & 7);
    const u16* gA = A  + (size_t)(m0 + srow) * GK + c16 * 8;
    const u16* gB = Bw + (size_t)(n0 + srow) * GK + c16 * 8;
    int sB = wv * 1024;

    int aBase = (wr * 16 + (lane & 15)) * 128;
    int bBase = (wc * 16 + (lane & 15)) * 128;
    int sw0 = (((lane >> 4))     ^ (lane & 7)) << 4;
    int sw1 = (((lane >> 4) + 4) ^ (lane & 7)) << 4;

    f32x4 acc[8][4] = {};

    // prologue: tile0 full {A0,B0,A1,B1} (8 loads) + tile1 {A0,B0,B1}
    // (6 loads); vmcnt(6) -> tile0 done; A1(1) staged in Ph1(0).
    stage_half(gA, lds + sB,                 0,   0);   // A0(0)
    stage_half(gB, lds + 65536 + sB,         0,   0);   // B0(0)
    stage_half(gA, lds + 16384 + sB,         128, 0);   // A1(0)
    stage_half(gB, lds + 65536 + 16384 + sB, 128, 0);   // B1(0)
    stage_half(gA, lds + 32768 + sB,         0,   1);   // A0(1)
    stage_half(gB, lds + 65536 + 32768 + sB, 0,   1);   // B0(1)
    stage_half(gB, lds + 98304 + 16384 + sB, 128, 1);   // B1(1)
    asm volatile("s_waitcnt vmcnt(6)" ::: "memory");
    BAR();

    for (int tt = 0; tt < 64; tt += 2) {
        ktile4<0>(tt,     lds, gA, gB, sB, aBase, bBase, sw0, sw1, acc);
        ktile4<1>(tt + 1, lds, gA, gB, sB, aBase, bBase, sw0, sw1, acc);
    }

    int cr = (lane >> 4) * 4;
    int cc = lane & 15;
    #pragma unroll
    for (int mh = 0; mh < 2; ++mh)
        #pragma unroll
        for (int mj = 0; mj < 4; ++mj)
            #pragma unroll
            for (int nh = 0; nh < 2; ++nh)
                #pragma unroll
                for (int nj = 0; nj < 2; ++nj) {
                    float* cp = C + (size_t)(m0 + mh * 128 + wr * 16 + mj * 32 + cr) * GN
                                  + (n0 + nh * 128 + wc * 16 + nj * 64 + cc);
                    #pragma unroll
                    for (int j = 0; j < 4; ++j)
                        __builtin_nontemporal_store(acc[mh * 4 + mj][nh * 2 + nj][j],
                                                    cp + (size_t)j * GN);
                }
}

// ---------------------------------------------------------------------------
// Tail path: 128x256 tile, full-K, 3-deep 144 KiB LDS, 2 phases/K-tile,
// vmcnt(6); single end-of-phase barrier. (r10-verified, unchanged)
// ---------------------------------------------------------------------------
template<int BUF>
__device__ __forceinline__ void ktile2(int t, char* lds,
                                       const u16* gA, const u16* gB,
                                       int sB, int aBase, int bBase, int sw0, int sw1,
                                       f32x4 (&acc)[4][4]) {
    const int AB  = BUF * 16384;
    const int BB  = 49152 + BUF * 32768;
    const int NB  = (BUF + 2 >= 3) ? (BUF - 1) : (BUF + 2);
    const int ABn = NB * 16384;
    const int BBn = 49152 + NB * 32768;

    bf16x8 aF[4][2], bF[2][2];
    bool s2 = (t < 62);

    // ---- phase 1: reads aF+b0F; stage A(t+2),B0(t+2); MFMA nj0,1
    #pragma unroll
    for (int mj = 0; mj < 4; ++mj) {
        aF[mj][0] = *(const bf16x8*)(lds + AB + aBase + mj * 4096 + sw0);
        aF[mj][1] = *(const bf16x8*)(lds + AB + aBase + mj * 4096 + sw1);
    }
    #pragma unroll
    for (int nj = 0; nj < 2; ++nj) {
        bF[nj][0] = *(const bf16x8*)(lds + BB + bBase + nj * 8192 + sw0);
        bF[nj][1] = *(const bf16x8*)(lds + BB + bBase + nj * 8192 + sw1);
    }
    if (s2) {
        stage_half(gA, lds + ABn + sB, 0, t + 2);
        stage_half(gB, lds + BBn + sB, 0, t + 2);
    }
    SCHED0();
    __builtin_amdgcn_s_setprio(1);
    #pragma unroll
    for (int mj = 0; mj < 4; ++mj)
        #pragma unroll
        for (int nj = 0; nj < 2; ++nj)
            #pragma unroll
            for (int kk = 0; kk < 2; ++kk)
                acc[mj][nj] = __builtin_amdgcn_mfma_f32_16x16x32_bf16(
                    aF[mj][kk], bF[nj][kk], acc[mj][nj], 0, 0, 0);
    __builtin_amdgcn_s_setprio(0);
    BAR();

    // ---- phase 2: reads b1F; stage B1(t+2); MFMA nj2,3; vmcnt(6)
    #pragma unroll
    for (int nj = 0; nj < 2; ++nj) {
        bF[nj][0] = *(const bf16x8*)(lds + BB + 16384 + bBase + nj * 8192 + sw0);
        bF[nj][1] = *(const bf16x8*)(lds + BB + 16384 + bBase + nj * 8192 + sw1);
    }
    if (s2) stage_half(gB, lds + BBn + 16384 + sB, 128, t + 2);
    SCHED0();
    __builtin_amdgcn_s_setprio(1);
    #pragma unroll
    for (int mj = 0; mj < 4; ++mj)
        #pragma unroll
        for (int nj = 0; nj < 2; ++nj)
            #pragma unroll
            for (int kk = 0; kk < 2; ++kk)
                acc[mj][2 + nj] = __builtin_amdgcn_mfma_f32_16x16x32_bf16(
                    aF[mj][kk], bF[nj][kk], acc[mj][2 + nj], 0, 0, 0);
    __builtin_amdgcn_s_setprio(0);
    if (s2) { asm volatile("s_waitcnt vmcnt(6)" ::: "memory"); }
    else    { asm volatile("s_waitcnt vmcnt(0)" ::: "memory"); }
    BAR();
}

__device__ __forceinline__ void gemm_tail(int bid, int tid, char* lds,
                                          const u16* A, const u16* Bw, float* C) {
    int lane = tid & 63;
    int wv   = tid >> 6;
    int wr   = wv >> 2;
    int wc   = wv & 3;

    // n-grouped mapping: XCD x mostly handles n-tile x (B slice L2-shared)
    int x = bid & 7, s = bid >> 3;             // s in 0..21
    int nt, mh;
    if (s < 16) { nt = x; mh = s; }
    else { int idx = (s - 16) * 8 + x; nt = 8 + (idx >> 4); mh = idx & 15; }
    int m0  = mh * 128;
    int n0  = 8192 + nt * 256;

    int srow = tid >> 3;
    int c16  = (tid & 7) ^ (srow & 7);
    const u16* gA = A  + (size_t)(m0 + srow) * GK + c16 * 8;
    const u16* gB = Bw + (size_t)(n0 + srow) * GK + c16 * 8;
    int sB = wv * 1024;

    int aBase = (wr * 16 + (lane & 15)) * 128;
    int bBase = (wc * 16 + (lane & 15)) * 128;
    int sw0 = (((lane >> 4))     ^ (lane & 7)) << 4;
    int sw1 = (((lane >> 4) + 4) ^ (lane & 7)) << 4;

    f32x4 acc[4][4] = {};

    stage_half(gA, lds + sB,                 0,   0);
    stage_half(gB, lds + 49152 + sB,         0,   0);
    stage_half(gB, lds + 49152 + 16384 + sB, 128, 0);
    stage_half(gA, lds + 16384 + sB,         0,   1);
    stage_half(gB, lds + 81920 + sB,         0,   1);
    stage_half(gB, lds + 81920 + 16384 + sB, 128, 1);
    asm volatile("s_waitcnt vmcnt(6)" ::: "memory");
    BAR();

    for (int tt = 0; tt < 63; tt += 3) {
        ktile2<0>(tt,     lds, gA, gB, sB, aBase, bBase, sw0, sw1, acc);
        ktile2<1>(tt + 1, lds, gA, gB, sB, aBase, bBase, sw0, sw1, acc);
        ktile2<2>(tt + 2, lds, gA, gB, sB, aBase, bBase, sw0, sw1, acc);
    }
    ktile2<0>(63, lds, gA, gB, sB, aBase, bBase, sw0, sw1, acc);

    int cr = (lane >> 4) * 4;
    int cc = lane & 15;
    #pragma unroll
    for (int mj = 0; mj < 4; ++mj)
        #pragma unroll
        for (int nj = 0; nj < 4; ++nj) {
            float* cp = C + (size_t)(m0 + wr * 16 + mj * 32 + cr) * GN
                          + (n0 + wc * 16 + nj * 64 + cc);
            #pragma unroll
            for (int j = 0; j < 4; ++j)
                __builtin_nontemporal_store(acc[mj][nj][j], cp + (size_t)j * GN);
        }
}

// ---------------------------------------------------------------------------
// Merged GEMM: 432 blocks. 0..255 = 256x256 full tiles (n < 8192),
// 256..431 = 128x256 full-K tail tiles (n >= 8192). LPT order.
// ---------------------------------------------------------------------------
__global__ __launch_bounds__(512, 1) void gemm_all_kernel(
    const u16* __restrict__ A, const u16* __restrict__ Bw,
    float* __restrict__ C) {
    extern __shared__ char lds[];
    int bid = blockIdx.x;
    if (bid < 256) gemm_big (bid,       threadIdx.x, lds, A, Bw, C);
    else           gemm_tail(bid - 256, threadIdx.x, lds, A, Bw, C);
}

// ---------------------------------------------------------------------------
extern "C" void kernel_launch(void* const* d_in, const int* in_sizes, int n_in,
                              void* d_out, int out_size, void* d_ws, size_t ws_size,
                              hipStream_t stream) {
    const float* x      = (const float*)d_in[0];
    const void*  packed = d_in[1];
    const float* norms  = (const float*)d_in[2];
    const float* s1     = (const float*)d_in[4];
    const float* s2     = (const float*)d_in[5];
    float* out          = (float*)d_out;

    size_t rx_bytes = (size_t)GM * GK * 2;
    size_t wq_bytes = (size_t)GN * GK * 2;
    if (ws_size < rx_bytes + wq_bytes) return;

    u16* rx = (u16*)d_ws;
    u16* wq = rx + (size_t)GM * GK;

    prep_kernel<<<dim3(ROT_BLOCKS + DQ_BLOCKS), dim3(256), 0, stream>>>(
        x, s1, s2, (u32*)rx, (const u32*)packed, norms, wq);

    hipFuncSetAttribute((const void*)gemm_all_kernel,
                        hipFuncAttributeMaxDynamicSharedMemorySize, 147456);
    gemm_all_kernel<<<dim3(432), dim3(512), 147456, stream>>>(rx, wq, out);
}

// Round 12
// 206.146 us; speedup vs baseline: 1.0750x; 1.0040x over previous
//
#include <hip/hip_runtime.h>

typedef unsigned int u32;
typedef unsigned short u16;

typedef short bf16x8 __attribute__((ext_vector_type(8)));
typedef float f32x4 __attribute__((ext_vector_type(4)));

#define GM 2048      // B
#define GN 11008     // O
#define GK 4096      // I
#define NGRP 32      // N = I/G
#define GSZ 128      // G

#define CAST_G(p) ((const __attribute__((address_space(1))) void*)(p))
#define CAST_L(p) ((__attribute__((address_space(3))) void*)(p))
#define BAR() __builtin_amdgcn_s_barrier()
#define SCHED0() __builtin_amdgcn_sched_barrier(0)

__device__ __forceinline__ u16 f2bf(float f) {
    u32 u = __builtin_bit_cast(u32, f);
    u32 r = (u + 0x7FFFu + ((u >> 16) & 1u)) >> 16;
    return (u16)r;
}

// ---------------------------------------------------------------------------
// Prep (merged): rotate x -> rx (bf16) AND dequant packed 3-bit -> wq bf16.
// ~21.6 us measured at the ~156 MB traffic roofline. (unchanged)
// ---------------------------------------------------------------------------
__device__ __forceinline__ float cent3(int i) {
    int m3 = (i >= 4) ? (i - 4) : (3 - i);
    float mag = (m3 >= 2) ? ((m3 == 3) ? 2.1519f : 1.3439f)
                          : ((m3 == 1) ? 0.756f  : 0.2451f);
    return (i >= 4) ? mag : -mag;
}

#define ROT_BLOCKS (GM * NGRP / 4)             // 16384
#define DQ_BLOCKS  (GN * NGRP * 4 / 256)       // 5504

__global__ __launch_bounds__(256) void prep_kernel(
    const float* __restrict__ x, const float* __restrict__ s1,
    const float* __restrict__ s2, u32* __restrict__ rx,
    const u32* __restrict__ p32, const float* __restrict__ norms,
    u16* __restrict__ wq) {
    if (blockIdx.x < ROT_BLOCKS) {
        int gid  = blockIdx.x * 256 + threadIdx.x;
        int grp  = gid >> 6;
        int lane = gid & 63;

        const float2* xp = (const float2*)(x + (size_t)grp * GSZ);
        float2 xv  = xp[lane];
        float2 s1v = ((const float2*)s1)[lane];
        float2 s2v = ((const float2*)s2)[lane];

        float e0 = xv.x * s1v.x;
        float e1 = xv.y * s1v.y;
        {
            float a = e0 + e1, b = e0 - e1;
            e0 = a; e1 = b;
        }
        #pragma unroll
        for (int hb = 1; hb <= 32; hb <<= 1) {
            float t0 = __shfl_xor(e0, hb, 64);
            float t1 = __shfl_xor(e1, hb, 64);
            bool up = (lane & hb) != 0;
            e0 = up ? (t0 - e0) : (e0 + t0);
            e1 = up ? (t1 - e1) : (e1 + t1);
        }
        const float inv = 0.08838834764831845f;   // 1/sqrt(128)
        u32 lo = f2bf(e0 * s2v.x * inv);
        u32 hi = f2bf(e1 * s2v.y * inv);
        rx[gid] = lo | (hi << 16);
    } else {
        int u = (blockIdx.x - ROT_BLOCKS) * 256 + threadIdx.x;
        int g_idx = u >> 2;

        float scale = norms[g_idx] * 0.08838834764831845f;

        u32 w0 = p32[(size_t)u * 3 + 0];
        u32 w1 = p32[(size_t)u * 3 + 1];
        u32 w2 = p32[(size_t)u * 3 + 2];

        u32 tri[4];
        if (((w0 | w1 | w2) & 0xFFFFFF00u) == 0u) {
            const u32* pi = p32 + (size_t)u * 12;
            u32 b[12];
            #pragma unroll
            for (int k = 0; k < 12; ++k) b[k] = pi[k];
            #pragma unroll
            for (int t = 0; t < 4; ++t)
                tri[t] = b[3*t] | (b[3*t+1] << 8) | (b[3*t+2] << 16);
        } else {
            tri[0] = w0 & 0xFFFFFFu;
            tri[1] = (w0 >> 24) | ((w1 & 0xFFFFu) << 8);
            tri[2] = (w1 >> 16) | ((w2 & 0xFFu) << 16);
            tri[3] = w2 >> 8;
        }

        u32 ow[16];
        #pragma unroll
        for (int t = 0; t < 4; ++t) {
            u32 v = tri[t];
            #pragma unroll
            for (int k = 0; k < 4; ++k) {
                int i0 = (int)((v >> (6*k))     & 7u);
                int i1 = (int)((v >> (6*k + 3)) & 7u);
                u32 lo = f2bf(cent3(i0) * scale);
                u32 hi = f2bf(cent3(i1) * scale);
                ow[t*4 + k] = lo | (hi << 16);
            }
        }
        u32* op = (u32*)(wq + (size_t)u * 32);
        #pragma unroll
        for (int k = 0; k < 16; ++k) op[k] = ow[k];
    }
}

// ---------------------------------------------------------------------------
// Shared: async half-tile staging (64 rows x 64 cols bf16 per call)
// ---------------------------------------------------------------------------
__device__ __forceinline__ void stage_half(const u16* g, char* ldst, int rowOff, int tt) {
    __builtin_amdgcn_global_load_lds(CAST_G(g + (size_t)rowOff * GK + tt * 64),
                                     CAST_L(ldst), 16, 0, 0);
    __builtin_amdgcn_global_load_lds(CAST_G(g + (size_t)(rowOff + 64) * GK + tt * 64),
                                     CAST_L(ldst + 8192), 16, 0, 0);
}

// ---------------------------------------------------------------------------
// Big path: 256x256 tile, BK=64, 2 phases/K-tile, 2-deep 128 KiB LDS,
// single vmcnt(6)/tile, T2 both-sides XOR swizzle, T5 setprio.
// r12 micros: (1) kk-OUTERMOST MFMA order (16 independent MFMAs between
// dependent acc uses); (2) stages moved AFTER the MFMA cluster (before
// vmcnt/BAR) so MFMA issue isn't delayed by gload addr VALU. Inter-phase
// ordering, vmcnt counts, and hazard separations identical to r11.
// ---------------------------------------------------------------------------
template<int BUF>
__device__ __forceinline__ void ktile4(int t, char* lds,
                                       const u16* gA, const u16* gB,
                                       int sB, int aBase, int bBase, int sw0, int sw1,
                                       f32x4 (&acc)[8][4]) {
    const int AB  = BUF * 32768;
    const int ABo = (BUF ^ 1) * 32768;
    const int BB  = 65536 + BUF * 32768;

    bf16x8 aF[4][2], b0F[2][2], b1F[2][2];
    bool s1 = (t < 63), s2 = (t < 62);

    // ---- Phase 1: mh0 x {nh0, nh1}
    #pragma unroll
    for (int mj = 0; mj < 4; ++mj) {
        aF[mj][0] = *(const bf16x8*)(lds + AB + aBase + mj * 4096 + sw0);
        aF[mj][1] = *(const bf16x8*)(lds + AB + aBase + mj * 4096 + sw1);
    }
    #pragma unroll
    for (int nj = 0; nj < 2; ++nj) {
        b0F[nj][0] = *(const bf16x8*)(lds + BB + bBase + nj * 8192 + sw0);
        b0F[nj][1] = *(const bf16x8*)(lds + BB + bBase + nj * 8192 + sw1);
    }
    #pragma unroll
    for (int nj = 0; nj < 2; ++nj) {
        b1F[nj][0] = *(const bf16x8*)(lds + BB + 16384 + bBase + nj * 8192 + sw0);
        b1F[nj][1] = *(const bf16x8*)(lds + BB + 16384 + bBase + nj * 8192 + sw1);
    }
    SCHED0();
    __builtin_amdgcn_s_setprio(1);
    #pragma unroll
    for (int kk = 0; kk < 2; ++kk) {
        #pragma unroll
        for (int mj = 0; mj < 4; ++mj)
            #pragma unroll
            for (int nj = 0; nj < 2; ++nj)
                acc[mj][nj] = __builtin_amdgcn_mfma_f32_16x16x32_bf16(
                    aF[mj][kk], b0F[nj][kk], acc[mj][nj], 0, 0, 0);
        #pragma unroll
        for (int mj = 0; mj < 4; ++mj)
            #pragma unroll
            for (int nj = 0; nj < 2; ++nj)
                acc[mj][2 + nj] = __builtin_amdgcn_mfma_f32_16x16x32_bf16(
                    aF[mj][kk], b1F[nj][kk], acc[mj][2 + nj], 0, 0, 0);
    }
    __builtin_amdgcn_s_setprio(0);
    if (s1) stage_half(gA, lds + ABo + 16384 + sB, 128, t + 1);   // A1(t+1)
    BAR();

    // ---- Phase 2: mh1 x {nh0, nh1}
    #pragma unroll
    for (int mj = 0; mj < 4; ++mj) {
        aF[mj][0] = *(const bf16x8*)(lds + AB + 16384 + aBase + mj * 4096 + sw0);
        aF[mj][1] = *(const bf16x8*)(lds + AB + 16384 + aBase + mj * 4096 + sw1);
    }
    SCHED0();
    __builtin_amdgcn_s_setprio(1);
    #pragma unroll
    for (int kk = 0; kk < 2; ++kk) {
        #pragma unroll
        for (int mj = 0; mj < 4; ++mj)
            #pragma unroll
            for (int nj = 0; nj < 2; ++nj)
                acc[4 + mj][nj] = __builtin_amdgcn_mfma_f32_16x16x32_bf16(
                    aF[mj][kk], b0F[nj][kk], acc[4 + mj][nj], 0, 0, 0);
        #pragma unroll
        for (int mj = 0; mj < 4; ++mj)
            #pragma unroll
            for (int nj = 0; nj < 2; ++nj)
                acc[4 + mj][2 + nj] = __builtin_amdgcn_mfma_f32_16x16x32_bf16(
                    aF[mj][kk], b1F[nj][kk], acc[4 + mj][2 + nj], 0, 0, 0);
    }
    __builtin_amdgcn_s_setprio(0);
    if (s2) {
        stage_half(gA, lds + AB + sB,         0,   t + 2);        // A0(t+2)
        stage_half(gB, lds + BB + sB,         0,   t + 2);        // B0(t+2)
        stage_half(gB, lds + BB + 16384 + sB, 128, t + 2);        // B1(t+2)
    }
    if (s2) { asm volatile("s_waitcnt vmcnt(6)" ::: "memory"); }
    else    { asm volatile("s_waitcnt vmcnt(0)" ::: "memory"); }
    BAR();
}

__device__ __forceinline__ void gemm_big(int tau, int tid, char* lds,
                                         const u16* A, const u16* Bw, float* C) {
    int lane = tid & 63;
    int wv   = tid >> 6;
    int wr   = wv >> 2;
    int wc   = wv & 3;

    // n-pinned XCD mapping: XCD x handles n-tiles {x, x+8, x+16, x+24} x all
    // m-tiles; each B K-slice fetched once per XCD (L2-served 8x).
    int n0 = (tau & 31) * 256;
    int m0 = (tau >> 5) * 256;

    int srow = tid >> 3;
    int c16  = (tid & 7) ^ (srow & 7);
    const u16* gA = A  + (size_t)(m0 + srow) * GK + c16 * 8;
    const u16* gB = Bw + (size_t)(n0 + srow) * GK + c16 * 8;
    int sB = wv * 1024;

    int aBase = (wr * 16 + (lane & 15)) * 128;
    int bBase = (wc * 16 + (lane & 15)) * 128;
    int sw0 = (((lane >> 4))     ^ (lane & 7)) << 4;
    int sw1 = (((lane >> 4) + 4) ^ (lane & 7)) << 4;

    f32x4 acc[8][4] = {};

    // prologue: tile0 full {A0,B0,A1,B1} (8 loads) + tile1 {A0,B0,B1}
    // (6 loads); vmcnt(6) -> tile0 done; A1(1) staged in Ph1(0).
    stage_half(gA, lds + sB,                 0,   0);   // A0(0)
    stage_half(gB, lds + 65536 + sB,         0,   0);   // B0(0)
    stage_half(gA, lds + 16384 + sB,         128, 0);   // A1(0)
    stage_half(gB, lds + 65536 + 16384 + sB, 128, 0);   // B1(0)
    stage_half(gA, lds + 32768 + sB,         0,   1);   // A0(1)
    stage_half(gB, lds + 65536 + 32768 + sB, 0,   1);   // B0(1)
    stage_half(gB, lds + 98304 + 16384 + sB, 128, 1);   // B1(1)
    asm volatile("s_waitcnt vmcnt(6)" ::: "memory");
    BAR();

    for (int tt = 0; tt < 64; tt += 2) {
        ktile4<0>(tt,     lds, gA, gB, sB, aBase, bBase, sw0, sw1, acc);
        ktile4<1>(tt + 1, lds, gA, gB, sB, aBase, bBase, sw0, sw1, acc);
    }

    int cr = (lane >> 4) * 4;
    int cc = lane & 15;
    #pragma unroll
    for (int mh = 0; mh < 2; ++mh)
        #pragma unroll
        for (int mj = 0; mj < 4; ++mj)
            #pragma unroll
            for (int nh = 0; nh < 2; ++nh)
                #pragma unroll
                for (int nj = 0; nj < 2; ++nj) {
                    float* cp = C + (size_t)(m0 + mh * 128 + wr * 16 + mj * 32 + cr) * GN
                                  + (n0 + nh * 128 + wc * 16 + nj * 64 + cc);
                    #pragma unroll
                    for (int j = 0; j < 4; ++j)
                        __builtin_nontemporal_store(acc[mh * 4 + mj][nh * 2 + nj][j],
                                                    cp + (size_t)j * GN);
                }
}

// ---------------------------------------------------------------------------
// Tail path: 128x256 tile, full-K, 3-deep 144 KiB LDS, 2 phases/K-tile,
// vmcnt(6); single end-of-phase barrier. r12 micros applied (kk-outer,
// stages after MFMA).
// ---------------------------------------------------------------------------
template<int BUF>
__device__ __forceinline__ void ktile2(int t, char* lds,
                                       const u16* gA, const u16* gB,
                                       int sB, int aBase, int bBase, int sw0, int sw1,
                                       f32x4 (&acc)[4][4]) {
    const int AB  = BUF * 16384;
    const int BB  = 49152 + BUF * 32768;
    const int NB  = (BUF + 2 >= 3) ? (BUF - 1) : (BUF + 2);
    const int ABn = NB * 16384;
    const int BBn = 49152 + NB * 32768;

    bf16x8 aF[4][2], bF[2][2];
    bool s2 = (t < 62);

    // ---- phase 1: reads aF+b0F; MFMA nj0,1; stage A(t+2),B0(t+2)
    #pragma unroll
    for (int mj = 0; mj < 4; ++mj) {
        aF[mj][0] = *(const bf16x8*)(lds + AB + aBase + mj * 4096 + sw0);
        aF[mj][1] = *(const bf16x8*)(lds + AB + aBase + mj * 4096 + sw1);
    }
    #pragma unroll
    for (int nj = 0; nj < 2; ++nj) {
        bF[nj][0] = *(const bf16x8*)(lds + BB + bBase + nj * 8192 + sw0);
        bF[nj][1] = *(const bf16x8*)(lds + BB + bBase + nj * 8192 + sw1);
    }
    SCHED0();
    __builtin_amdgcn_s_setprio(1);
    #pragma unroll
    for (int kk = 0; kk < 2; ++kk)
        #pragma unroll
        for (int mj = 0; mj < 4; ++mj)
            #pragma unroll
            for (int nj = 0; nj < 2; ++nj)
                acc[mj][nj] = __builtin_amdgcn_mfma_f32_16x16x32_bf16(
                    aF[mj][kk], bF[nj][kk], acc[mj][nj], 0, 0, 0);
    __builtin_amdgcn_s_setprio(0);
    if (s2) {
        stage_half(gA, lds + ABn + sB, 0, t + 2);
        stage_half(gB, lds + BBn + sB, 0, t + 2);
    }
    BAR();

    // ---- phase 2: reads b1F; MFMA nj2,3; stage B1(t+2); vmcnt(6)
    #pragma unroll
    for (int nj = 0; nj < 2; ++nj) {
        bF[nj][0] = *(const bf16x8*)(lds + BB + 16384 + bBase + nj * 8192 + sw0);
        bF[nj][1] = *(const bf16x8*)(lds + BB + 16384 + bBase + nj * 8192 + sw1);
    }
    SCHED0();
    __builtin_amdgcn_s_setprio(1);
    #pragma unroll
    for (int kk = 0; kk < 2; ++kk)
        #pragma unroll
        for (int mj = 0; mj < 4; ++mj)
            #pragma unroll
            for (int nj = 0; nj < 2; ++nj)
                acc[mj][2 + nj] = __builtin_amdgcn_mfma_f32_16x16x32_bf16(
                    aF[mj][kk], bF[nj][kk], acc[mj][2 + nj], 0, 0, 0);
    __builtin_amdgcn_s_setprio(0);
    if (s2) stage_half(gB, lds + BBn + 16384 + sB, 128, t + 2);
    if (s2) { asm volatile("s_waitcnt vmcnt(6)" ::: "memory"); }
    else    { asm volatile("s_waitcnt vmcnt(0)" ::: "memory"); }
    BAR();
}

__device__ __forceinline__ void gemm_tail(int bid, int tid, char* lds,
                                          const u16* A, const u16* Bw, float* C) {
    int lane = tid & 63;
    int wv   = tid >> 6;
    int wr   = wv >> 2;
    int wc   = wv & 3;

    // n-grouped mapping: XCD x mostly handles n-tile x (B slice L2-shared)
    int x = bid & 7, s = bid >> 3;             // s in 0..21
    int nt, mh;
    if (s < 16) { nt = x; mh = s; }
    else { int idx = (s - 16) * 8 + x; nt = 8 + (idx >> 4); mh = idx & 15; }
    int m0  = mh * 128;
    int n0  = 8192 + nt * 256;

    int srow = tid >> 3;
    int c16  = (tid & 7) ^ (srow & 7);
    const u16* gA = A  + (size_t)(m0 + srow) * GK + c16 * 8;
    const u16* gB = Bw + (size_t)(n0 + srow) * GK + c16 * 8;
    int sB = wv * 1024;

    int aBase = (wr * 16 + (lane & 15)) * 128;
    int bBase = (wc * 16 + (lane & 15)) * 128;
    int sw0 = (((lane >> 4))     ^ (lane & 7)) << 4;
    int sw1 = (((lane >> 4) + 4) ^ (lane & 7)) << 4;

    f32x4 acc[4][4] = {};

    stage_half(gA, lds + sB,                 0,   0);
    stage_half(gB, lds + 49152 + sB,         0,   0);
    stage_half(gB, lds + 49152 + 16384 + sB, 128, 0);
    stage_half(gA, lds + 16384 + sB,         0,   1);
    stage_half(gB, lds + 81920 + sB,         0,   1);
    stage_half(gB, lds + 81920 + 16384 + sB, 128, 1);
    asm volatile("s_waitcnt vmcnt(6)" ::: "memory");
    BAR();

    for (int tt = 0; tt < 63; tt += 3) {
        ktile2<0>(tt,     lds, gA, gB, sB, aBase, bBase, sw0, sw1, acc);
        ktile2<1>(tt + 1, lds, gA, gB, sB, aBase, bBase, sw0, sw1, acc);
        ktile2<2>(tt + 2, lds, gA, gB, sB, aBase, bBase, sw0, sw1, acc);
    }
    ktile2<0>(63, lds, gA, gB, sB, aBase, bBase, sw0, sw1, acc);

    int cr = (lane >> 4) * 4;
    int cc = lane & 15;
    #pragma unroll
    for (int mj = 0; mj < 4; ++mj)
        #pragma unroll
        for (int nj = 0; nj < 4; ++nj) {
            float* cp = C + (size_t)(m0 + wr * 16 + mj * 32 + cr) * GN
                          + (n0 + wc * 16 + nj * 64 + cc);
            #pragma unroll
            for (int j = 0; j < 4; ++j)
                __builtin_nontemporal_store(acc[mj][nj][j], cp + (size_t)j * GN);
        }
}

// ---------------------------------------------------------------------------
// Merged GEMM: 432 blocks. 0..255 = 256x256 full tiles (n < 8192),
// 256..431 = 128x256 full-K tail tiles (n >= 8192). LPT order.
// ---------------------------------------------------------------------------
__global__ __launch_bounds__(512, 1) void gemm_all_kernel(
    const u16* __restrict__ A, const u16* __restrict__ Bw,
    float* __restrict__ C) {
    extern __shared__ char lds[];
    int bid = blockIdx.x;
    if (bid < 256) gemm_big (bid,       threadIdx.x, lds, A, Bw, C);
    else           gemm_tail(bid - 256, threadIdx.x, lds, A, Bw, C);
}

// ---------------------------------------------------------------------------
extern "C" void kernel_launch(void* const* d_in, const int* in_sizes, int n_in,
                              void* d_out, int out_size, void* d_ws, size_t ws_size,
                              hipStream_t stream) {
    const float* x      = (const float*)d_in[0];
    const void*  packed = d_in[1];
    const float* norms  = (const float*)d_in[2];
    const float* s1     = (const float*)d_in[4];
    const float* s2     = (const float*)d_in[5];
    float* out          = (float*)d_out;

    size_t rx_bytes = (size_t)GM * GK * 2;
    size_t wq_bytes = (size_t)GN * GK * 2;
    if (ws_size < rx_bytes + wq_bytes) return;

    u16* rx = (u16*)d_ws;
    u16* wq = rx + (size_t)GM * GK;

    prep_kernel<<<dim3(ROT_BLOCKS + DQ_BLOCKS), dim3(256), 0, stream>>>(
        x, s1, s2, (u32*)rx, (const u32*)packed, norms, wq);

    hipFuncSetAttribute((const void*)gemm_all_kernel,
                        hipFuncAttributeMaxDynamicSharedMemorySize, 147456);
    gemm_all_kernel<<<dim3(432), dim3(512), 147456, stream>>>(rx, wq, out);
}

// Round 13
// 202.750 us; speedup vs baseline: 1.0930x; 1.0168x over previous
//
#include <hip/hip_runtime.h>

typedef unsigned int u32;
typedef unsigned short u16;

typedef short bf16x8 __attribute__((ext_vector_type(8)));
typedef float f32x4 __attribute__((ext_vector_type(4)));

#define GM 2048      // B
#define GN 11008     // O
#define GK 4096      // I
#define NGRP 32      // N = I/G
#define GSZ 128      // G

#define CAST_G(p) ((const __attribute__((address_space(1))) void*)(p))
#define CAST_L(p) ((__attribute__((address_space(3))) void*)(p))
#define BAR() __builtin_amdgcn_s_barrier()
#define SCHED0() __builtin_amdgcn_sched_barrier(0)

__device__ __forceinline__ u16 f2bf(float f) {
    u32 u = __builtin_bit_cast(u32, f);
    u32 r = (u + 0x7FFFu + ((u >> 16) & 1u)) >> 16;
    return (u16)r;
}

// ---------------------------------------------------------------------------
// Prep (merged): rotate x -> rx (bf16) AND dequant packed 3-bit -> wq bf16.
// ~21.6 us measured at the ~156 MB traffic roofline. (unchanged)
// ---------------------------------------------------------------------------
__device__ __forceinline__ float cent3(int i) {
    int m3 = (i >= 4) ? (i - 4) : (3 - i);
    float mag = (m3 >= 2) ? ((m3 == 3) ? 2.1519f : 1.3439f)
                          : ((m3 == 1) ? 0.756f  : 0.2451f);
    return (i >= 4) ? mag : -mag;
}

#define ROT_BLOCKS (GM * NGRP / 4)             // 16384
#define DQ_BLOCKS  (GN * NGRP * 4 / 256)       // 5504

__global__ __launch_bounds__(256) void prep_kernel(
    const float* __restrict__ x, const float* __restrict__ s1,
    const float* __restrict__ s2, u32* __restrict__ rx,
    const u32* __restrict__ p32, const float* __restrict__ norms,
    u16* __restrict__ wq) {
    if (blockIdx.x < ROT_BLOCKS) {
        int gid  = blockIdx.x * 256 + threadIdx.x;
        int grp  = gid >> 6;
        int lane = gid & 63;

        const float2* xp = (const float2*)(x + (size_t)grp * GSZ);
        float2 xv  = xp[lane];
        float2 s1v = ((const float2*)s1)[lane];
        float2 s2v = ((const float2*)s2)[lane];

        float e0 = xv.x * s1v.x;
        float e1 = xv.y * s1v.y;
        {
            float a = e0 + e1, b = e0 - e1;
            e0 = a; e1 = b;
        }
        #pragma unroll
        for (int hb = 1; hb <= 32; hb <<= 1) {
            float t0 = __shfl_xor(e0, hb, 64);
            float t1 = __shfl_xor(e1, hb, 64);
            bool up = (lane & hb) != 0;
            e0 = up ? (t0 - e0) : (e0 + t0);
            e1 = up ? (t1 - e1) : (e1 + t1);
        }
        const float inv = 0.08838834764831845f;   // 1/sqrt(128)
        u32 lo = f2bf(e0 * s2v.x * inv);
        u32 hi = f2bf(e1 * s2v.y * inv);
        rx[gid] = lo | (hi << 16);
    } else {
        int u = (blockIdx.x - ROT_BLOCKS) * 256 + threadIdx.x;
        int g_idx = u >> 2;

        float scale = norms[g_idx] * 0.08838834764831845f;

        u32 w0 = p32[(size_t)u * 3 + 0];
        u32 w1 = p32[(size_t)u * 3 + 1];
        u32 w2 = p32[(size_t)u * 3 + 2];

        u32 tri[4];
        if (((w0 | w1 | w2) & 0xFFFFFF00u) == 0u) {
            const u32* pi = p32 + (size_t)u * 12;
            u32 b[12];
            #pragma unroll
            for (int k = 0; k < 12; ++k) b[k] = pi[k];
            #pragma unroll
            for (int t = 0; t < 4; ++t)
                tri[t] = b[3*t] | (b[3*t+1] << 8) | (b[3*t+2] << 16);
        } else {
            tri[0] = w0 & 0xFFFFFFu;
            tri[1] = (w0 >> 24) | ((w1 & 0xFFFFu) << 8);
            tri[2] = (w1 >> 16) | ((w2 & 0xFFu) << 16);
            tri[3] = w2 >> 8;
        }

        u32 ow[16];
        #pragma unroll
        for (int t = 0; t < 4; ++t) {
            u32 v = tri[t];
            #pragma unroll
            for (int k = 0; k < 4; ++k) {
                int i0 = (int)((v >> (6*k))     & 7u);
                int i1 = (int)((v >> (6*k + 3)) & 7u);
                u32 lo = f2bf(cent3(i0) * scale);
                u32 hi = f2bf(cent3(i1) * scale);
                ow[t*4 + k] = lo | (hi << 16);
            }
        }
        u32* op = (u32*)(wq + (size_t)u * 32);
        #pragma unroll
        for (int k = 0; k < 16; ++k) op[k] = ow[k];
    }
}

// ---------------------------------------------------------------------------
// Shared: async half-tile staging (64 rows x 64 cols bf16 per call)
// ---------------------------------------------------------------------------
__device__ __forceinline__ void stage_half(const u16* g, char* ldst, int rowOff, int tt) {
    __builtin_amdgcn_global_load_lds(CAST_G(g + (size_t)rowOff * GK + tt * 64),
                                     CAST_L(ldst), 16, 0, 0);
    __builtin_amdgcn_global_load_lds(CAST_G(g + (size_t)(rowOff + 64) * GK + tt * 64),
                                     CAST_L(ldst + 8192), 16, 0, 0);
}

// ---------------------------------------------------------------------------
// Big path: 256x256 tile, BK=64, 2 phases/K-tile, **A 3-deep / B 2-deep**
// (160 KiB LDS: A bufs 0/32/64K, B bufs 96/128K), single vmcnt(6)/tile,
// T2 both-sides XOR swizzle, T5 setprio. r13 change vs r12: prefetch cover —
// A(t+2) staged during t, waited end of t+1 (3-4 phases, covers L3 latency);
// B0(t+2) 2 phases; B1(t+1) 1.5 phases (B is L2-resident, short latency).
// Stage stream: Ph1{B1(t+1)->otherB, A0(t+2)->A[(t+2)%3]},
//               Ph2{B0(t+2)->B[t%2], A1(t+2)} ; vmcnt(6) at tile end.
// Queue invariant: enter 6 -> +4 -> +4 =14 -> vmcnt(6) completes tile t+1.
// Restage-vs-read: every region's stage >=1 BAR after its last reads.
// ---------------------------------------------------------------------------
template<int AB_I, int BB_I>
__device__ __forceinline__ void ktile4(int t, char* lds,
                                       const u16* gA, const u16* gB,
                                       int sB, int aBase, int bBase, int sw0, int sw1,
                                       f32x4 (&acc)[8][4]) {
    const int AB  = AB_I * 32768;                       // A, current buf
    const int ABn = ((AB_I + 2) % 3) * 32768;           // A, stage target t+2
    const int BB  = 98304 + BB_I * 32768;               // B, current buf
    const int BBo = 98304 + (BB_I ^ 1) * 32768;         // B, other buf (t+1)

    bf16x8 aF[4][2], b0F[2][2], b1F[2][2];
    bool s1 = (t < 63), s2 = (t < 62);

    // ---- Phase 1: mh0 x {nh0, nh1}
    #pragma unroll
    for (int mj = 0; mj < 4; ++mj) {
        aF[mj][0] = *(const bf16x8*)(lds + AB + aBase + mj * 4096 + sw0);
        aF[mj][1] = *(const bf16x8*)(lds + AB + aBase + mj * 4096 + sw1);
    }
    #pragma unroll
    for (int nj = 0; nj < 2; ++nj) {
        b0F[nj][0] = *(const bf16x8*)(lds + BB + bBase + nj * 8192 + sw0);
        b0F[nj][1] = *(const bf16x8*)(lds + BB + bBase + nj * 8192 + sw1);
    }
    #pragma unroll
    for (int nj = 0; nj < 2; ++nj) {
        b1F[nj][0] = *(const bf16x8*)(lds + BB + 16384 + bBase + nj * 8192 + sw0);
        b1F[nj][1] = *(const bf16x8*)(lds + BB + 16384 + bBase + nj * 8192 + sw1);
    }
    SCHED0();
    __builtin_amdgcn_s_setprio(1);
    #pragma unroll
    for (int kk = 0; kk < 2; ++kk) {
        #pragma unroll
        for (int mj = 0; mj < 4; ++mj)
            #pragma unroll
            for (int nj = 0; nj < 2; ++nj)
                acc[mj][nj] = __builtin_amdgcn_mfma_f32_16x16x32_bf16(
                    aF[mj][kk], b0F[nj][kk], acc[mj][nj], 0, 0, 0);
        #pragma unroll
        for (int mj = 0; mj < 4; ++mj)
            #pragma unroll
            for (int nj = 0; nj < 2; ++nj)
                acc[mj][2 + nj] = __builtin_amdgcn_mfma_f32_16x16x32_bf16(
                    aF[mj][kk], b1F[nj][kk], acc[mj][2 + nj], 0, 0, 0);
    }
    __builtin_amdgcn_s_setprio(0);
    if (s1) stage_half(gB, lds + BBo + 16384 + sB, 128, t + 1);   // B1(t+1)
    if (s2) stage_half(gA, lds + ABn + sB,         0,   t + 2);   // A0(t+2)
    BAR();

    // ---- Phase 2: mh1 x {nh0, nh1}
    #pragma unroll
    for (int mj = 0; mj < 4; ++mj) {
        aF[mj][0] = *(const bf16x8*)(lds + AB + 16384 + aBase + mj * 4096 + sw0);
        aF[mj][1] = *(const bf16x8*)(lds + AB + 16384 + aBase + mj * 4096 + sw1);
    }
    SCHED0();
    __builtin_amdgcn_s_setprio(1);
    #pragma unroll
    for (int kk = 0; kk < 2; ++kk) {
        #pragma unroll
        for (int mj = 0; mj < 4; ++mj)
            #pragma unroll
            for (int nj = 0; nj < 2; ++nj)
                acc[4 + mj][nj] = __builtin_amdgcn_mfma_f32_16x16x32_bf16(
                    aF[mj][kk], b0F[nj][kk], acc[4 + mj][nj], 0, 0, 0);
        #pragma unroll
        for (int mj = 0; mj < 4; ++mj)
            #pragma unroll
            for (int nj = 0; nj < 2; ++nj)
                acc[4 + mj][2 + nj] = __builtin_amdgcn_mfma_f32_16x16x32_bf16(
                    aF[mj][kk], b1F[nj][kk], acc[4 + mj][2 + nj], 0, 0, 0);
    }
    __builtin_amdgcn_s_setprio(0);
    if (s2) {
        stage_half(gB, lds + BB + sB,          0,   t + 2);       // B0(t+2)
        stage_half(gA, lds + ABn + 16384 + sB, 128, t + 2);       // A1(t+2)
    }
    if (s2) { asm volatile("s_waitcnt vmcnt(6)" ::: "memory"); }
    else    { asm volatile("s_waitcnt vmcnt(0)" ::: "memory"); }
    BAR();
}

__device__ __forceinline__ void gemm_big(int tau, int tid, char* lds,
                                         const u16* A, const u16* Bw, float* C) {
    int lane = tid & 63;
    int wv   = tid >> 6;
    int wr   = wv >> 2;
    int wc   = wv & 3;

    // n-pinned XCD mapping: XCD x handles n-tiles {x, x+8, x+16, x+24} x all
    // m-tiles; each B K-slice fetched once per XCD (L2-served 8x).
    int n0 = (tau & 31) * 256;
    int m0 = (tau >> 5) * 256;

    int srow = tid >> 3;
    int c16  = (tid & 7) ^ (srow & 7);
    const u16* gA = A  + (size_t)(m0 + srow) * GK + c16 * 8;
    const u16* gB = Bw + (size_t)(n0 + srow) * GK + c16 * 8;
    int sB = wv * 1024;

    int aBase = (wr * 16 + (lane & 15)) * 128;
    int bBase = (wc * 16 + (lane & 15)) * 128;
    int sw0 = (((lane >> 4))     ^ (lane & 7)) << 4;
    int sw1 = (((lane >> 4) + 4) ^ (lane & 7)) << 4;

    f32x4 acc[8][4] = {};

    // prologue: A(0)->buf0, B(0)->buf0, A(1)->buf1, B0(1)->buf1 = 14 loads;
    // vmcnt(6) completes first 8 (= all of tile 0); outstanding 6 =
    // {A0(1),A1(1),B0(1)} -> steady-state invariant entering ph1(0).
    stage_half(gA, lds + sB,                  0,   0);   // A0(0)
    stage_half(gA, lds + 16384 + sB,          128, 0);   // A1(0)
    stage_half(gB, lds + 98304 + sB,          0,   0);   // B0(0)
    stage_half(gB, lds + 98304 + 16384 + sB,  128, 0);   // B1(0)
    stage_half(gA, lds + 32768 + sB,          0,   1);   // A0(1)
    stage_half(gA, lds + 32768 + 16384 + sB,  128, 1);   // A1(1)
    stage_half(gB, lds + 131072 + sB,         0,   1);   // B0(1)
    asm volatile("s_waitcnt vmcnt(6)" ::: "memory");
    BAR();

    // buf pattern (t%3, t%2) has period 6: 64 = 6*10 + 4
    for (int tt = 0; tt < 60; tt += 6) {
        ktile4<0,0>(tt,     lds, gA, gB, sB, aBase, bBase, sw0, sw1, acc);
        ktile4<1,1>(tt + 1, lds, gA, gB, sB, aBase, bBase, sw0, sw1, acc);
        ktile4<2,0>(tt + 2, lds, gA, gB, sB, aBase, bBase, sw0, sw1, acc);
        ktile4<0,1>(tt + 3, lds, gA, gB, sB, aBase, bBase, sw0, sw1, acc);
        ktile4<1,0>(tt + 4, lds, gA, gB, sB, aBase, bBase, sw0, sw1, acc);
        ktile4<2,1>(tt + 5, lds, gA, gB, sB, aBase, bBase, sw0, sw1, acc);
    }
    ktile4<0,0>(60, lds, gA, gB, sB, aBase, bBase, sw0, sw1, acc);
    ktile4<1,1>(61, lds, gA, gB, sB, aBase, bBase, sw0, sw1, acc);
    ktile4<2,0>(62, lds, gA, gB, sB, aBase, bBase, sw0, sw1, acc);
    ktile4<0,1>(63, lds, gA, gB, sB, aBase, bBase, sw0, sw1, acc);

    int cr = (lane >> 4) * 4;
    int cc = lane & 15;
    #pragma unroll
    for (int mh = 0; mh < 2; ++mh)
        #pragma unroll
        for (int mj = 0; mj < 4; ++mj)
            #pragma unroll
            for (int nh = 0; nh < 2; ++nh)
                #pragma unroll
                for (int nj = 0; nj < 2; ++nj) {
                    float* cp = C + (size_t)(m0 + mh * 128 + wr * 16 + mj * 32 + cr) * GN
                                  + (n0 + nh * 128 + wc * 16 + nj * 64 + cc);
                    #pragma unroll
                    for (int j = 0; j < 4; ++j)
                        __builtin_nontemporal_store(acc[mh * 4 + mj][nh * 2 + nj][j],
                                                    cp + (size_t)j * GN);
                }
}

// ---------------------------------------------------------------------------
// Tail path: 128x256 tile, full-K, 3-deep 144 KiB LDS, 2 phases/K-tile,
// vmcnt(6); single end-of-phase barrier. (r12-verified, unchanged)
// ---------------------------------------------------------------------------
template<int BUF>
__device__ __forceinline__ void ktile2(int t, char* lds,
                                       const u16* gA, const u16* gB,
                                       int sB, int aBase, int bBase, int sw0, int sw1,
                                       f32x4 (&acc)[4][4]) {
    const int AB  = BUF * 16384;
    const int BB  = 49152 + BUF * 32768;
    const int NB  = (BUF + 2 >= 3) ? (BUF - 1) : (BUF + 2);
    const int ABn = NB * 16384;
    const int BBn = 49152 + NB * 32768;

    bf16x8 aF[4][2], bF[2][2];
    bool s2 = (t < 62);

    #pragma unroll
    for (int mj = 0; mj < 4; ++mj) {
        aF[mj][0] = *(const bf16x8*)(lds + AB + aBase + mj * 4096 + sw0);
        aF[mj][1] = *(const bf16x8*)(lds + AB + aBase + mj * 4096 + sw1);
    }
    #pragma unroll
    for (int nj = 0; nj < 2; ++nj) {
        bF[nj][0] = *(const bf16x8*)(lds + BB + bBase + nj * 8192 + sw0);
        bF[nj][1] = *(const bf16x8*)(lds + BB + bBase + nj * 8192 + sw1);
    }
    SCHED0();
    __builtin_amdgcn_s_setprio(1);
    #pragma unroll
    for (int kk = 0; kk < 2; ++kk)
        #pragma unroll
        for (int mj = 0; mj < 4; ++mj)
            #pragma unroll
            for (int nj = 0; nj < 2; ++nj)
                acc[mj][nj] = __builtin_amdgcn_mfma_f32_16x16x32_bf16(
                    aF[mj][kk], bF[nj][kk], acc[mj][nj], 0, 0, 0);
    __builtin_amdgcn_s_setprio(0);
    if (s2) {
        stage_half(gA, lds + ABn + sB, 0, t + 2);
        stage_half(gB, lds + BBn + sB, 0, t + 2);
    }
    BAR();

    #pragma unroll
    for (int nj = 0; nj < 2; ++nj) {
        bF[nj][0] = *(const bf16x8*)(lds + BB + 16384 + bBase + nj * 8192 + sw0);
        bF[nj][1] = *(const bf16x8*)(lds + BB + 16384 + bBase + nj * 8192 + sw1);
    }
    SCHED0();
    __builtin_amdgcn_s_setprio(1);
    #pragma unroll
    for (int kk = 0; kk < 2; ++kk)
        #pragma unroll
        for (int mj = 0; mj < 4; ++mj)
            #pragma unroll
            for (int nj = 0; nj < 2; ++nj)
                acc[mj][2 + nj] = __builtin_amdgcn_mfma_f32_16x16x32_bf16(
                    aF[mj][kk], bF[nj][kk], acc[mj][2 + nj], 0, 0, 0);
    __builtin_amdgcn_s_setprio(0);
    if (s2) stage_half(gB, lds + BBn + 16384 + sB, 128, t + 2);
    if (s2) { asm volatile("s_waitcnt vmcnt(6)" ::: "memory"); }
    else    { asm volatile("s_waitcnt vmcnt(0)" ::: "memory"); }
    BAR();
}

__device__ __forceinline__ void gemm_tail(int bid, int tid, char* lds,
                                          const u16* A, const u16* Bw, float* C) {
    int lane = tid & 63;
    int wv   = tid >> 6;
    int wr   = wv >> 2;
    int wc   = wv & 3;

    // n-grouped mapping: XCD x mostly handles n-tile x (B slice L2-shared)
    int x = bid & 7, s = bid >> 3;             // s in 0..21
    int nt, mh;
    if (s < 16) { nt = x; mh = s; }
    else { int idx = (s - 16) * 8 + x; nt = 8 + (idx >> 4); mh = idx & 15; }
    int m0  = mh * 128;
    int n0  = 8192 + nt * 256;

    int srow = tid >> 3;
    int c16  = (tid & 7) ^ (srow & 7);
    const u16* gA = A  + (size_t)(m0 + srow) * GK + c16 * 8;
    const u16* gB = Bw + (size_t)(n0 + srow) * GK + c16 * 8;
    int sB = wv * 1024;

    int aBase = (wr * 16 + (lane & 15)) * 128;
    int bBase = (wc * 16 + (lane & 15)) * 128;
    int sw0 = (((lane >> 4))     ^ (lane & 7)) << 4;
    int sw1 = (((lane >> 4) + 4) ^ (lane & 7)) << 4;

    f32x4 acc[4][4] = {};

    stage_half(gA, lds + sB,                 0,   0);
    stage_half(gB, lds + 49152 + sB,         0,   0);
    stage_half(gB, lds + 49152 + 16384 + sB, 128, 0);
    stage_half(gA, lds + 16384 + sB,         0,   1);
    stage_half(gB, lds + 81920 + sB,         0,   1);
    stage_half(gB, lds + 81920 + 16384 + sB, 128, 1);
    asm volatile("s_waitcnt vmcnt(6)" ::: "memory");
    BAR();

    for (int tt = 0; tt < 63; tt += 3) {
        ktile2<0>(tt,     lds, gA, gB, sB, aBase, bBase, sw0, sw1, acc);
        ktile2<1>(tt + 1, lds, gA, gB, sB, aBase, bBase, sw0, sw1, acc);
        ktile2<2>(tt + 2, lds, gA, gB, sB, aBase, bBase, sw0, sw1, acc);
    }
    ktile2<0>(63, lds, gA, gB, sB, aBase, bBase, sw0, sw1, acc);

    int cr = (lane >> 4) * 4;
    int cc = lane & 15;
    #pragma unroll
    for (int mj = 0; mj < 4; ++mj)
        #pragma unroll
        for (int nj = 0; nj < 4; ++nj) {
            float* cp = C + (size_t)(m0 + wr * 16 + mj * 32 + cr) * GN
                          + (n0 + wc * 16 + nj * 64 + cc);
            #pragma unroll
            for (int j = 0; j < 4; ++j)
                __builtin_nontemporal_store(acc[mj][nj][j], cp + (size_t)j * GN);
        }
}

// ---------------------------------------------------------------------------
// Merged GEMM: 432 blocks. 0..255 = 256x256 full tiles (n < 8192),
// 256..431 = 128x256 full-K tail tiles (n >= 8192). LPT order.
// ---------------------------------------------------------------------------
__global__ __launch_bounds__(512, 1) void gemm_all_kernel(
    const u16* __restrict__ A, const u16* __restrict__ Bw,
    float* __restrict__ C) {
    extern __shared__ char lds[];
    int bid = blockIdx.x;
    if (bid < 256) gemm_big (bid,       threadIdx.x, lds, A, Bw, C);
    else           gemm_tail(bid - 256, threadIdx.x, lds, A, Bw, C);
}

// ---------------------------------------------------------------------------
extern "C" void kernel_launch(void* const* d_in, const int* in_sizes, int n_in,
                              void* d_out, int out_size, void* d_ws, size_t ws_size,
                              hipStream_t stream) {
    const float* x      = (const float*)d_in[0];
    const void*  packed = d_in[1];
    const float* norms  = (const float*)d_in[2];
    const float* s1     = (const float*)d_in[4];
    const float* s2     = (const float*)d_in[5];
    float* out          = (float*)d_out;

    size_t rx_bytes = (size_t)GM * GK * 2;
    size_t wq_bytes = (size_t)GN * GK * 2;
    if (ws_size < rx_bytes + wq_bytes) return;

    u16* rx = (u16*)d_ws;
    u16* wq = rx + (size_t)GM * GK;

    prep_kernel<<<dim3(ROT_BLOCKS + DQ_BLOCKS), dim3(256), 0, stream>>>(
        x, s1, s2, (u32*)rx, (const u32*)packed, norms, wq);

    hipFuncSetAttribute((const void*)gemm_all_kernel,
                        hipFuncAttributeMaxDynamicSharedMemorySize, 163840);
    gemm_all_kernel<<<dim3(432), dim3(512), 163840, stream>>>(rx, wq, out);
}